// Round 10
// baseline (204.169 us; speedup 1.0000x reference)
//
#include <hip/hip_runtime.h>

typedef _Float16 h8 __attribute__((ext_vector_type(8)));
typedef _Float16 h4 __attribute__((ext_vector_type(4)));
typedef float f4 __attribute__((ext_vector_type(4)));

#define NB 2
#define NT 2048
#define NC 1024
#define NH 16
#define DKK 64
#define DV 176
#define DVP 256
#define OFF 64
#define KV 2112   // OFF + NT
#define SCALE_Q 0.18033688011112f   // log2(e)/8, folded into q
#define CLAMP_S 11.541560327111f    // 8*log2(e)

__device__ __forceinline__ void load_lds16(const _Float16* g, _Float16* l) {
    __builtin_amdgcn_global_load_lds(
        (const __attribute__((address_space(1))) void*)g,
        (__attribute__((address_space(3))) void*)l, 16, 0, 0);
}

// ---------------- fused prep A: f32->f16 casts + rotb zero ----------------
// vec4 items: x 1048576 | wqk 524288 | wv 720896 | rotb 180224  (total 2473984)
#define PREPA_X   1048576
#define PREPA_QK  1572864   // + 524288
#define PREPA_WV  2293760   // + 720896
#define PREPA_END 2473984   // + 180224
__global__ __launch_bounds__(256)
void k_prep_a(const float* __restrict__ x, const float* __restrict__ wqk,
              const float* __restrict__ wv, _Float16* __restrict__ xh,
              _Float16* __restrict__ wqkh, _Float16* __restrict__ wvh,
              float* __restrict__ rotb) {
    int i = blockIdx.x * 256 + threadIdx.x;
    if (i >= PREPA_END) return;
    if (i < PREPA_X) {
        float4 v = *(const float4*)(x + (size_t)i * 4);
        h4 h = {(_Float16)v.x, (_Float16)v.y, (_Float16)v.z, (_Float16)v.w};
        *(h4*)(xh + (size_t)i * 4) = h;
    } else if (i < PREPA_QK) {
        int j = i - PREPA_X;
        float4 v = *(const float4*)(wqk + (size_t)j * 4);
        h4 h = {(_Float16)v.x, (_Float16)v.y, (_Float16)v.z, (_Float16)v.w};
        *(h4*)(wqkh + (size_t)j * 4) = h;
    } else if (i < PREPA_WV) {
        int j = i - PREPA_QK;
        float4 v = *(const float4*)(wv + (size_t)j * 4);
        h4 h = {(_Float16)v.x, (_Float16)v.y, (_Float16)v.z, (_Float16)v.w};
        *(h4*)(wvh + (size_t)j * 4) = h;
    } else {
        int j = i - PREPA_WV;
        *(float4*)(rotb + (size_t)j * 4) = (float4){0.f, 0.f, 0.f, 0.f};
    }
}

// ---------------- fused prep B: KV-cache copies + V pad ----------------
// vec4 items: ck 32768 | cv 131072 | zpad 1310720  (total 1474560)
#define PREPB_CK   32768
#define PREPB_CV   163840    // + 131072
#define PREPB_END  1474560   // + 1310720
__global__ __launch_bounds__(256)
void k_prep_b(const float* __restrict__ ck, const float* __restrict__ cv,
              float* __restrict__ out_k, _Float16* __restrict__ kh,
              float* __restrict__ out_v, _Float16* __restrict__ vTh) {
    int i = blockIdx.x * 256 + threadIdx.x;
    if (i >= PREPB_END) return;
    if (i < PREPB_CK) {
        // cached_k (B,H,64,64): 1024 vec4 per bh (4096 floats)
        int bh = i >> 10, rem = i & 1023;
        int pos = rem >> 4, d4 = (rem & 15) * 4;
        float4 v = *(const float4*)(ck + (size_t)i * 4);
        size_t o = ((size_t)bh * KV + pos) * DKK + d4;
        *(float4*)(out_k + o) = v;
        h4 h = {(_Float16)v.x, (_Float16)v.y, (_Float16)v.z, (_Float16)v.w};
        *(h4*)(kh + o) = h;
    } else if (i < PREPB_CV) {
        // cached_v (B,H,64,256): 4096 vec4 per bh (16384 floats)
        int j = i - PREPB_CK;
        int bh = j >> 12, rem = j & 4095;
        int pos = rem >> 6, c4 = (rem & 63) * 4;
        float4 v = *(const float4*)(cv + (size_t)j * 4);
        *(float4*)(out_v + ((size_t)bh * KV + pos) * DVP + c4) = v;
        if (c4 < DV) {
            _Float16* vt = vTh + ((size_t)bh * DV + c4) * KV + pos;
            vt[0]              = (_Float16)v.x;
            vt[KV]             = (_Float16)v.y;
            vt[2 * (size_t)KV] = (_Float16)v.z;
            vt[3 * (size_t)KV] = (_Float16)v.w;
        }
    } else {
        // zero pad cols [176,256) of out_v rows [64,2112): 20 vec4 per row
        int j = i - PREPB_CV;
        int bh = j / 40960, rem = j - bh * 40960;
        int t = rem / 20, c4 = DV + (rem - t * 20) * 4;
        *(float4*)(out_v + ((size_t)bh * KV + OFF + t) * DVP + c4) = (float4){0.f, 0.f, 0.f, 0.f};
    }
}

// ---------------- fused GEMM: [q|k|v] = x @ W^T ----------------
// BK=64 (16 barrier rounds), swizzled [128][64] LDS (both-sides XOR).
// N = 4864 = 38 tiles (0-7 q, 8-15 k, 16-37 v). grid 1216; XCD x owns an
// 8mi x 19ni super-rect. Epilogue LDS buffers union As/Bs.
__global__ __launch_bounds__(256)
void k_gemm_fused(const _Float16* __restrict__ xh, const _Float16* __restrict__ wh,
                  _Float16* __restrict__ qh, _Float16* __restrict__ kh,
                  float* __restrict__ out_k, _Float16* __restrict__ vTh,
                  float* __restrict__ out_v) {
    __shared__ char smem_raw[36864];
    auto As = (_Float16(*)[64])smem_raw;               // [128][64] swizzled
    auto Bs = (_Float16(*)[64])(smem_raw + 16384);     // [128][64] swizzled
    auto Ts = (_Float16(*)[64][72])smem_raw;           // [4][64][72] (v epilogue)
    auto Tq = (_Float16(*)[128][68])smem_raw;          // [2][128][68] (q/k epilogue)

    const int tid = threadIdx.x;
    const int lane = tid & 63, w = tid >> 6;
    const int lr = lane & 15, lg = lane >> 4;
    const int wm = w >> 1, wn = w & 1;
    const int n = blockIdx.x, x = n & 7, idx = n >> 3;
    const int mi = (x & 3) * 8 + idx / 19;
    const int ni = (x >> 2) * 19 + idx % 19;
    const int m0 = mi * 128, n0 = ni * 128;
    const int srow = lane >> 3;                        // 0..7 row within chunk
    const int sc16 = (lane & 7) ^ srow;                // pre-swizzled col16

    f4 acc[4][4];
#pragma unroll
    for (int i = 0; i < 4; i++)
#pragma unroll
        for (int j = 0; j < 4; j++) acc[i][j] = (f4){0.f, 0.f, 0.f, 0.f};

    for (int k0 = 0; k0 < NC; k0 += 64) {
        __syncthreads();
#pragma unroll
        for (int j = 0; j < 4; j++) {
            int i = w * 4 + j;
            int row = i * 8 + srow;
            load_lds16(&xh[(size_t)(m0 + row) * NC + k0 + sc16 * 8],
                       (_Float16*)As + i * 512);
            load_lds16(&wh[(size_t)(n0 + row) * NC + k0 + sc16 * 8],
                       (_Float16*)Bs + i * 512);
        }
        asm volatile("s_waitcnt vmcnt(0)" ::: "memory");
        __syncthreads();

#pragma unroll
        for (int ks = 0; ks < 2; ks++) {
            h8 a[4], b[4];
#pragma unroll
            for (int mt = 0; mt < 4; mt++) {
                int row = wm * 64 + mt * 16 + lr;
                a[mt] = *(const h8*)&As[row][((ks * 4 + lg) ^ (lr & 7)) * 8];
            }
#pragma unroll
            for (int nt = 0; nt < 4; nt++) {
                int row = wn * 64 + nt * 16 + lr;
                b[nt] = *(const h8*)&Bs[row][((ks * 4 + lg) ^ (lr & 7)) * 8];
            }
#pragma unroll
            for (int mt = 0; mt < 4; mt++)
#pragma unroll
                for (int nt = 0; nt < 4; nt++)
                    acc[mt][nt] = __builtin_amdgcn_mfma_f32_16x16x32_f16(a[mt], b[nt], acc[mt][nt], 0, 0, 0);
        }
    }

    const int b_ = m0 >> 11;
    const int mloc = m0 & (NT - 1);

    if (ni < 8) {
        // ---- q tile: stage f16 (pre-scaled) into Tq, stream out coalesced ----
        __syncthreads();   // all waves done with As/Bs
#pragma unroll
        for (int mt = 0; mt < 4; mt++)
#pragma unroll
            for (int nt = 0; nt < 4; nt++)
#pragma unroll
                for (int r = 0; r < 4; r++)
                    Tq[wn][wm * 64 + mt * 16 + lg * 4 + r][nt * 16 + lr] =
                        (_Float16)(acc[mt][nt][r] * SCALE_Q);
        __syncthreads();
        const int h0 = n0 >> 6;
#pragma unroll
        for (int i = 0; i < 8; i++) {
            int id = i * 256 + tid;                  // 0..2047 chunks of 16B
            int hh = id >> 10, rem = id & 1023;
            int t = rem >> 3, dk8 = (rem & 7) * 8;
            h8 v = *(const h8*)&Tq[hh][t][dk8];
            *(h8*)&qh[((size_t)(b_ * NH + h0 + hh) * NT + mloc + t) * DKK + dk8] = v;
        }
    } else if (ni < 16) {
        // ---- k tile: f32 out_k direct + kh staged via Tq (coalesced) ----
        __syncthreads();   // all waves done with As/Bs
#pragma unroll
        for (int mt = 0; mt < 4; mt++)
#pragma unroll
            for (int nt = 0; nt < 4; nt++)
#pragma unroll
                for (int r = 0; r < 4; r++) {
                    int t = wm * 64 + mt * 16 + lg * 4 + r;
                    int g2 = n0 - 1024 + wn * 64 + nt * 16 + lr;
                    float v = acc[mt][nt][r];
                    int h = g2 >> 6, dk = g2 & 63;
                    out_k[((size_t)(b_ * NH + h) * KV + OFF + mloc + t) * DKK + dk] = v;
                    Tq[wn][t][nt * 16 + lr] = (_Float16)v;
                }
        __syncthreads();
        const int h0 = (n0 - 1024) >> 6;
#pragma unroll
        for (int i = 0; i < 8; i++) {
            int id = i * 256 + tid;
            int hh = id >> 10, rem = id & 1023;
            int t = rem >> 3, dk8 = (rem & 7) * 8;
            h8 v = *(const h8*)&Tq[hh][t][dk8];
            *(h8*)&kh[((size_t)(b_ * NH + h0 + hh) * KV + OFF + mloc + t) * DKK + dk8] = v;
        }
    } else {
        // ---- v tile: f32 out_v + vTh via LDS transpose (Ts unions As/Bs) ----
        __syncthreads();   // all waves done with As/Bs before Ts overwrite
#pragma unroll
        for (int mt = 0; mt < 4; mt++)
#pragma unroll
            for (int nt = 0; nt < 4; nt++) {
                h4 ph;
#pragma unroll
                for (int r = 0; r < 4; r++) {
                    int grow = m0 + wm * 64 + mt * 16 + lg * 4 + r;
                    int gcol = n0 - 2048 + wn * 64 + nt * 16 + lr;
                    float v = acc[mt][nt][r];
                    int bb = grow >> 11, t = grow & (NT - 1);
                    int h = gcol / DV;
                    int c = gcol - h * DV;
                    out_v[((size_t)(bb * NH + h) * KV + OFF + t) * DVP + c] = v;
                    ph[r] = (_Float16)v;
                }
                *(h4*)&Ts[w][nt * 16 + lr][mt * 16 + lg * 4] = ph;
            }
        __syncthreads();
        {
            _Float16* vout = vTh + ((size_t)b_ * (NH * DV) + (n0 - 2048)) * KV + OFF + mloc;
            const int seg = tid & 31;
            const int rr = tid >> 5;
#pragma unroll
            for (int i = 0; i < 16; i++) {
                int c = i * 8 + rr;
                int buf = ((seg >> 4) << 1) | (c >> 6);
                h4 vv = *(const h4*)&Ts[buf][c & 63][(seg & 15) * 4];
                *(h4*)&vout[(size_t)c * KV + seg * 4] = vv;
            }
        }
    }
}

// ---------------- flash attention + head-sum ----------------
// Block = 4 waves sharing one staged K/V tile; wave w handles qt = gq*4+w.
// SPLIT-DRAIN staging: issue K loads first, vmcnt(4) (own K done) -> barrier
// -> QK^T+softmax WHILE V loads fly -> vmcnt(0)+barrier -> PV. Fixed-max
// softmax in log2 domain. grid 1024 = 32 gq (desc) x 32 bh (XCD-affine).
__global__ __launch_bounds__(256, 4)
void k_attn(const _Float16* __restrict__ qh, const _Float16* __restrict__ kh,
            const _Float16* __restrict__ vTh, float* __restrict__ rot) {
    __shared__ _Float16 Ks[64][64];      // 8 KB  (swizzled)
    __shared__ _Float16 Vs[176][64];     // 22 KB (swizzled, V^T)
    __shared__ _Float16 Ps[4][16][72];   // 9.2 KB per-wave P
    const int tid = threadIdx.x, lane = tid & 63, w = tid >> 6;
    const int lr = lane & 15, lg = lane >> 4;
    const int n = blockIdx.x;
    const int gq = 31 - (n >> 5);                  // LPT: long first
    const int bh = (n & 7) + 8 * ((n >> 3) & 3);   // bh%8 == n%8 (XCD)
    const int b_ = bh >> 4;
    const int qt = gq * 4 + w;
    const int q = qt * 16 + lr;                    // this lane's softmax row

    const _Float16* qp = qh + ((size_t)bh * NT + q) * DKK;
    h8 bq0 = *(const h8*)(qp + lg * 8);
    h8 bq1 = *(const h8*)(qp + 32 + lg * 8);

    const _Float16* kbase = kh + (size_t)bh * KV * DKK;
    const _Float16* vbase = vTh + (size_t)bh * DV * KV;

    f4 o[11];
#pragma unroll
    for (int i = 0; i < 11; i++) o[i] = (f4){0.f, 0.f, 0.f, 0.f};
    float l_acc = 0.f;

    const int nkt = gq + 2;
    const int srow = lane >> 3, sslot = lane & 7;
    const int sc16 = sslot ^ srow;                 // pre-swizzled global col

    for (int kt = 0; kt < nkt; kt++) {
        __syncthreads();                            // everyone done reading prev tile
        // K loads issued FIRST (oldest in vmcnt queue)
#pragma unroll
        for (int j = 0; j < 2; j++) {
            int i = w * 2 + j;
            int row = i * 8 + srow;
            load_lds16(&kbase[(size_t)(kt * 64 + row) * DKK + sc16 * 8],
                       (_Float16*)Ks + i * 512);
        }
        // V loads after (up to 6 per wave; wave 3 has 4)
#pragma unroll
        for (int j = 0; j < 6; j++) {
            int i = w * 6 + j;
            if (i < 22) {
                int row = i * 8 + srow;
                load_lds16(&vbase[(size_t)row * KV + kt * 64 + sc16 * 8],
                           (_Float16*)Vs + i * 512);
            }
        }
        // own K done (wave3: 4 V outstanding -> oldest 2 = K; waves0-2: 2K+2V)
        asm volatile("s_waitcnt vmcnt(4)" ::: "memory");
        __syncthreads();                            // all K staged

        f4 s[4];
#pragma unroll
        for (int nt = 0; nt < 4; nt++) {
            int krow = nt * 16 + lr;
            h8 ak0 = *(const h8*)&Ks[krow][(lg ^ (lr & 7)) * 8];
            h8 ak1 = *(const h8*)&Ks[krow][((4 + lg) ^ (lr & 7)) * 8];
            f4 st = (f4){0.f, 0.f, 0.f, 0.f};
            st = __builtin_amdgcn_mfma_f32_16x16x32_f16(ak0, bq0, st, 0, 0, 0);
            st = __builtin_amdgcn_mfma_f32_16x16x32_f16(ak1, bq1, st, 0, 0, 0);
            s[nt] = st;
        }

#pragma unroll
        for (int nt = 0; nt < 4; nt++) {
            h4 ph;
#pragma unroll
            for (int r = 0; r < 4; r++) {
                int key = kt * 64 + nt * 16 + lg * 4 + r;
                float sv = fminf(s[nt][r], CLAMP_S);
                float p = (key <= q + OFF) ? __builtin_exp2f(sv) : 0.f;
                l_acc += p;
                ph[r] = (_Float16)p;
            }
            *(h4*)&Ps[w][lr][nt * 16 + lg * 4] = ph;
        }

        asm volatile("s_waitcnt vmcnt(0)" ::: "memory");   // own V done
        __syncthreads();                            // all V staged

#pragma unroll
        for (int ks = 0; ks < 2; ks++) {
            h8 ap = *(const h8*)&Ps[w][lr][ks * 32 + lg * 8];
#pragma unroll
            for (int nt = 0; nt < 11; nt++) {
                int vrow = nt * 16 + lr;
                h8 bv = *(const h8*)&Vs[vrow][((ks * 4 + lg) ^ (lr & 7)) * 8];
                o[nt] = __builtin_amdgcn_mfma_f32_16x16x32_f16(ap, bv, o[nt], 0, 0, 0);
            }
        }
    }

    l_acc += __shfl_xor(l_acc, 16);
    l_acc += __shfl_xor(l_acc, 32);
    float lq[4];
#pragma unroll
    for (int r = 0; r < 4; r++) lq[r] = 1.f / __shfl(l_acc, lg * 4 + r);
#pragma unroll
    for (int r = 0; r < 4; r++) {
        int t = qt * 16 + lg * 4 + r;
#pragma unroll
        for (int nt = 0; nt < 11; nt++) {
            atomicAdd(&rot[((size_t)b_ * NT + t) * DV + nt * 16 + lr], o[nt][r] * lq[r]);
        }
    }
}

// ---------------- per-token Kronecker rotation via expm ----------------
__device__ __forceinline__ int triu16(int r, int c) { return r * 15 - (r * (r - 1)) / 2 + (c - r - 1); }
__device__ __forceinline__ int triu8(int r, int c)  { return r * 7  - (r * (r - 1)) / 2 + (c - r - 1); }

__global__ __launch_bounds__(64)
void k_rotate(const float* __restrict__ x, const float* __restrict__ rot,
              float* __restrict__ y) {
    __shared__ float A16[16][16], Ta[16][16], Tb[16][16];
    __shared__ float A8[2][8][8], T8a[2][8][8], T8b[2][8][8];
    __shared__ float pbuf[176];
    __shared__ float xt[1024], t1[1024], t2[1024];
    const int tok = blockIdx.x;
    const int lane = threadIdx.x;

    for (int i = lane; i < 176; i += 64) pbuf[i] = rot[(size_t)tok * DV + i];
    for (int i = lane; i < 1024; i += 64) xt[i] = x[(size_t)tok * NC + i];
    __syncthreads();

#pragma unroll
    for (int j = 0; j < 4; j++) {
        int e = lane * 4 + j, r = e >> 4, c = e & 15;
        float v = 0.f;
        if (r < c) v = pbuf[triu16(r, c)];
        else if (r > c) v = -pbuf[triu16(c, r)];
        A16[r][c] = v;
    }
    {
        int r = lane >> 3, c = lane & 7;
#pragma unroll
        for (int m = 0; m < 2; m++) {
            float v = 0.f;
            if (r < c) v = pbuf[120 + m * 28 + triu8(r, c)];
            else if (r > c) v = -pbuf[120 + m * 28 + triu8(c, r)];
            A8[m][r][c] = v;
        }
    }
    __syncthreads();

    float rn = 0.f;
    if (lane < 16) {
#pragma unroll
        for (int c = 0; c < 16; c++) rn += fabsf(A16[lane][c]);
    }
#pragma unroll
    for (int mm = 1; mm < 16; mm <<= 1) rn = fmaxf(rn, __shfl_xor(rn, mm));
    rn = __shfl(rn, 0);
    int s = 0;
    while (rn > 0.5f && s < 60) { rn *= 0.5f; s++; }
    const float sc16 = exp2f((float)(-s));
    __syncthreads();
#pragma unroll
    for (int j = 0; j < 4; j++) { int e = lane * 4 + j; A16[e >> 4][e & 15] *= sc16; }
    __syncthreads();
#pragma unroll
    for (int j = 0; j < 4; j++) {
        int e = lane * 4 + j, r = e >> 4, c = e & 15;
        Ta[r][c] = (r == c ? 1.f : 0.f) + A16[r][c] * (1.f / 12.f);
    }
    __syncthreads();
    float (*Tc)[16] = Ta, (*Tn)[16] = Tb;
    for (int k = 11; k >= 1; k--) {
#pragma unroll
        for (int j = 0; j < 4; j++) {
            int e = lane * 4 + j, r = e >> 4, c = e & 15;
            float acc = 0.f;
#pragma unroll
            for (int q = 0; q < 16; q++) acc += A16[r][q] * Tc[q][c];
            Tn[r][c] = acc * (1.f / (float)k) + (r == c ? 1.f : 0.f);
        }
        __syncthreads();
        float (*tmp)[16] = Tc; Tc = Tn; Tn = tmp;
    }
    for (int it = 0; it < s; it++) {
#pragma unroll
        for (int j = 0; j < 4; j++) {
            int e = lane * 4 + j, r = e >> 4, c = e & 15;
            float acc = 0.f;
#pragma unroll
            for (int q = 0; q < 16; q++) acc += Tc[r][q] * Tc[q][c];
            Tn[r][c] = acc;
        }
        __syncthreads();
        float (*tmp)[16] = Tc; Tc = Tn; Tn = tmp;
    }

    float (*R2p)[8] = T8a[0];
    float (*R3p)[8] = T8a[1];
    {
        int r = lane >> 3, c = lane & 7;
        for (int m = 0; m < 2; m++) {
            float rn8 = 0.f;
            if (lane < 8) {
#pragma unroll
                for (int cc = 0; cc < 8; cc++) rn8 += fabsf(A8[m][lane][cc]);
            }
#pragma unroll
            for (int mm = 1; mm < 8; mm <<= 1) rn8 = fmaxf(rn8, __shfl_xor(rn8, mm));
            rn8 = __shfl(rn8, 0);
            int s8 = 0;
            while (rn8 > 0.5f && s8 < 60) { rn8 *= 0.5f; s8++; }
            float sc8 = exp2f((float)(-s8));
            __syncthreads();
            A8[m][r][c] *= sc8;
            __syncthreads();
            T8a[m][r][c] = (r == c ? 1.f : 0.f) + A8[m][r][c] * (1.f / 12.f);
            __syncthreads();
            float (*tc)[8] = T8a[m], (*tn)[8] = T8b[m];
            for (int k = 11; k >= 1; k--) {
                float acc = 0.f;
#pragma unroll
                for (int q = 0; q < 8; q++) acc += A8[m][r][q] * tc[q][c];
                tn[r][c] = acc * (1.f / (float)k) + (r == c ? 1.f : 0.f);
                __syncthreads();
                float (*tmp)[8] = tc; tc = tn; tn = tmp;
            }
            for (int it = 0; it < s8; it++) {
                float acc = 0.f;
#pragma unroll
                for (int q = 0; q < 8; q++) acc += tc[r][q] * tc[q][c];
                tn[r][c] = acc;
                __syncthreads();
                float (*tmp)[8] = tc; tc = tn; tn = tmp;
            }
            if (m == 0) R2p = tc; else R3p = tc;
        }
    }
    __syncthreads();

    for (int o = lane; o < 1024; o += 64) {
        int c = o & 7, base = o & ~7;
        float acc = 0.f;
#pragma unroll
        for (int j = 0; j < 8; j++) acc += R3p[c][j] * xt[base + j];
        t1[o] = acc;
    }
    __syncthreads();
    for (int o = lane; o < 1024; o += 64) {
        int c = o & 7, bb = (o >> 3) & 7, a = o >> 6;
        float acc = 0.f;
#pragma unroll
        for (int j = 0; j < 8; j++) acc += R2p[bb][j] * t1[a * 64 + j * 8 + c];
        t2[o] = acc;
    }
    __syncthreads();
    for (int o = lane; o < 1024; o += 64) {
        int rr = o & 63, a = o >> 6;
        float acc = 0.f;
#pragma unroll
        for (int j = 0; j < 16; j++) acc += Tc[a][j] * t2[j * 64 + rr];
        y[(size_t)tok * NC + o] = acc;
    }
}

// ---------------- launcher ----------------
extern "C" void kernel_launch(void* const* d_in, const int* in_sizes, int n_in,
                              void* d_out, int out_size, void* d_ws, size_t ws_size,
                              hipStream_t stream) {
    const float* x   = (const float*)d_in[0];
    const float* ck  = (const float*)d_in[1];
    const float* cv  = (const float*)d_in[2];
    const float* wqk = (const float*)d_in[3];
    const float* wv  = (const float*)d_in[4];

    float* out_y = (float*)d_out;
    float* out_k = out_y + (size_t)NB * NT * NC;
    float* out_v = out_k + (size_t)NB * NH * KV * DKK;

    char* ws = (char*)d_ws;
    _Float16* xh   = (_Float16*)ws;  ws += (size_t)NB * NT * NC * 2;
    _Float16* wqkh = (_Float16*)ws;  ws += (size_t)2 * NH * DKK * NC * 2;   // contiguous with wvh
    _Float16* wvh  = (_Float16*)ws;  ws += (size_t)NH * DV * NC * 2;
    _Float16* qh   = (_Float16*)ws;  ws += (size_t)NB * NH * NT * DKK * 2;
    _Float16* kh   = (_Float16*)ws;  ws += (size_t)NB * NH * KV * DKK * 2;
    _Float16* vTh  = (_Float16*)ws;  ws += (size_t)NB * NH * DV * KV * 2;
    float*    rotb = (float*)ws;     ws += (size_t)NB * NT * DV * 4;

    k_prep_a<<<dim3((PREPA_END + 255) / 256), dim3(256), 0, stream>>>(
        x, wqk, wv, xh, wqkh, wvh, rotb);
    k_prep_b<<<dim3((PREPB_END + 255) / 256), dim3(256), 0, stream>>>(
        ck, cv, out_k, kh, out_v, vTh);

    k_gemm_fused<<<dim3(1216), dim3(256), 0, stream>>>(xh, wqkh, qh, kh, out_k, vTh, out_v);

    k_attn<<<dim3(1024), dim3(256), 0, stream>>>(qh, kh, vTh, rotb);

    k_rotate<<<dim3(NB * NT), dim3(64), 0, stream>>>(x, rotb, out_y);
}

// Round 12
// 191.543 us; speedup vs baseline: 1.0659x; 1.0659x over previous
//
#include <hip/hip_runtime.h>

typedef _Float16 h8 __attribute__((ext_vector_type(8)));
typedef _Float16 h4 __attribute__((ext_vector_type(4)));
typedef float f4 __attribute__((ext_vector_type(4)));

#define NB 2
#define NT 2048
#define NC 1024
#define NH 16
#define DKK 64
#define DV 176
#define DVP 256
#define OFF 64
#define KV 2112   // OFF + NT
#define SCALE_Q 0.18033688011112f   // log2(e)/8, folded into q
#define CLAMP_S 11.541560327111f    // 8*log2(e)

__device__ __forceinline__ void load_lds16(const _Float16* g, _Float16* l) {
    __builtin_amdgcn_global_load_lds(
        (const __attribute__((address_space(1))) void*)g,
        (__attribute__((address_space(3))) void*)l, 16, 0, 0);
}

// ---------------- fused prep A: f32->f16 casts + rotb zero ----------------
// vec4 items: x 1048576 | wqk 524288 | wv 720896 | rotb 180224  (total 2473984)
#define PREPA_X   1048576
#define PREPA_QK  1572864   // + 524288
#define PREPA_WV  2293760   // + 720896
#define PREPA_END 2473984   // + 180224
__global__ __launch_bounds__(256)
void k_prep_a(const float* __restrict__ x, const float* __restrict__ wqk,
              const float* __restrict__ wv, _Float16* __restrict__ xh,
              _Float16* __restrict__ wqkh, _Float16* __restrict__ wvh,
              float* __restrict__ rotb) {
    int i = blockIdx.x * 256 + threadIdx.x;
    if (i >= PREPA_END) return;
    if (i < PREPA_X) {
        float4 v = *(const float4*)(x + (size_t)i * 4);
        h4 h = {(_Float16)v.x, (_Float16)v.y, (_Float16)v.z, (_Float16)v.w};
        *(h4*)(xh + (size_t)i * 4) = h;
    } else if (i < PREPA_QK) {
        int j = i - PREPA_X;
        float4 v = *(const float4*)(wqk + (size_t)j * 4);
        h4 h = {(_Float16)v.x, (_Float16)v.y, (_Float16)v.z, (_Float16)v.w};
        *(h4*)(wqkh + (size_t)j * 4) = h;
    } else if (i < PREPA_WV) {
        int j = i - PREPA_QK;
        float4 v = *(const float4*)(wv + (size_t)j * 4);
        h4 h = {(_Float16)v.x, (_Float16)v.y, (_Float16)v.z, (_Float16)v.w};
        *(h4*)(wvh + (size_t)j * 4) = h;
    } else {
        int j = i - PREPA_WV;
        *(float4*)(rotb + (size_t)j * 4) = (float4){0.f, 0.f, 0.f, 0.f};
    }
}

// ---------------- fused prep B: KV-cache copies + V pad ----------------
// vec4 items: ck 32768 | cv 131072 | zpad 1310720  (total 1474560)
#define PREPB_CK   32768
#define PREPB_CV   163840    // + 131072
#define PREPB_END  1474560   // + 1310720
__global__ __launch_bounds__(256)
void k_prep_b(const float* __restrict__ ck, const float* __restrict__ cv,
              float* __restrict__ out_k, _Float16* __restrict__ kh,
              float* __restrict__ out_v, _Float16* __restrict__ vTh) {
    int i = blockIdx.x * 256 + threadIdx.x;
    if (i >= PREPB_END) return;
    if (i < PREPB_CK) {
        // cached_k (B,H,64,64): 1024 vec4 per bh (4096 floats)
        int bh = i >> 10, rem = i & 1023;
        int pos = rem >> 4, d4 = (rem & 15) * 4;
        float4 v = *(const float4*)(ck + (size_t)i * 4);
        size_t o = ((size_t)bh * KV + pos) * DKK + d4;
        *(float4*)(out_k + o) = v;
        h4 h = {(_Float16)v.x, (_Float16)v.y, (_Float16)v.z, (_Float16)v.w};
        *(h4*)(kh + o) = h;
    } else if (i < PREPB_CV) {
        // cached_v (B,H,64,256): 4096 vec4 per bh (16384 floats)
        int j = i - PREPB_CK;
        int bh = j >> 12, rem = j & 4095;
        int pos = rem >> 6, c4 = (rem & 63) * 4;
        float4 v = *(const float4*)(cv + (size_t)j * 4);
        *(float4*)(out_v + ((size_t)bh * KV + pos) * DVP + c4) = v;
        if (c4 < DV) {
            _Float16* vt = vTh + ((size_t)bh * DV + c4) * KV + pos;
            vt[0]              = (_Float16)v.x;
            vt[KV]             = (_Float16)v.y;
            vt[2 * (size_t)KV] = (_Float16)v.z;
            vt[3 * (size_t)KV] = (_Float16)v.w;
        }
    } else {
        // zero pad cols [176,256) of out_v rows [64,2112): 20 vec4 per row
        int j = i - PREPB_CV;
        int bh = j / 40960, rem = j - bh * 40960;
        int t = rem / 20, c4 = DV + (rem - t * 20) * 4;
        *(float4*)(out_v + ((size_t)bh * KV + OFF + t) * DVP + c4) = (float4){0.f, 0.f, 0.f, 0.f};
    }
}

// ---------------- fused GEMM: [q|k|v] = x @ W^T ----------------
// BK=64, DOUBLE-BUFFERED staging, counted vmcnt(8) + raw s_barrier, with
// sched_barrier(0) pins (rule #18: raw s_barrier is IntrNoMem -> compiler
// may hoist ds_reads across it; the pins stop that — this was R11's race).
// Swizzled [128][64] LDS (both-sides XOR). N = 4864 = 38 tiles
// (0-7 q, 8-15 k, 16-37 v). grid 1216; XCD x owns an 8mi x 19ni rect.
__global__ __launch_bounds__(256)
void k_gemm_fused(const _Float16* __restrict__ xh, const _Float16* __restrict__ wh,
                  _Float16* __restrict__ qh, _Float16* __restrict__ kh,
                  float* __restrict__ out_k, _Float16* __restrict__ vTh,
                  float* __restrict__ out_v) {
    __shared__ char smem_raw[65536];
    // As buf b: bytes [b*16384, +16KB); Bs buf b: bytes [32768 + b*16384, +16KB)
    auto Ts = (_Float16(*)[64][72])smem_raw;           // [4][64][72] (v epilogue)
    auto Tq = (_Float16(*)[128][68])smem_raw;          // [2][128][68] (q/k epilogue)

    const int tid = threadIdx.x;
    const int lane = tid & 63, w = tid >> 6;
    const int lr = lane & 15, lg = lane >> 4;
    const int wm = w >> 1, wn = w & 1;
    const int n = blockIdx.x, x = n & 7, idx = n >> 3;
    const int mi = (x & 3) * 8 + idx / 19;
    const int ni = (x >> 2) * 19 + idx % 19;
    const int m0 = mi * 128, n0 = ni * 128;
    const int srow = lane >> 3;                        // 0..7 row within chunk
    const int sc16 = (lane & 7) ^ srow;                // pre-swizzled col16

    f4 acc[4][4];
#pragma unroll
    for (int i = 0; i < 4; i++)
#pragma unroll
        for (int j = 0; j < 4; j++) acc[i][j] = (f4){0.f, 0.f, 0.f, 0.f};

    // stage one 128x64 A-tile + B-tile into buffer `buf` (8 loads per wave)
    auto stage = [&](int buf, int k0) {
        _Float16* Ab = (_Float16*)smem_raw + buf * 8192;
        _Float16* Bb = (_Float16*)(smem_raw + 32768) + buf * 8192;
#pragma unroll
        for (int j = 0; j < 4; j++) {
            int i = w * 4 + j;
            int row = i * 8 + srow;
            load_lds16(&xh[(size_t)(m0 + row) * NC + k0 + sc16 * 8], Ab + i * 512);
            load_lds16(&wh[(size_t)(n0 + row) * NC + k0 + sc16 * 8], Bb + i * 512);
        }
    };

    stage(0, 0);
    int cur = 0;
    for (int t = 0; t < 16; ++t) {
        if (t < 15) {
            stage(cur ^ 1, (t + 1) * 64);
            asm volatile("s_waitcnt vmcnt(8)" ::: "memory");  // own stage(t) done
        } else {
            asm volatile("s_waitcnt vmcnt(0)" ::: "memory");
        }
        __builtin_amdgcn_s_barrier();          // all waves' stage(t) in LDS
        __builtin_amdgcn_sched_barrier(0);     // pin: no ds_read above barrier

        const _Float16* Ab = (const _Float16*)smem_raw + cur * 8192;
        const _Float16* Bb = (const _Float16*)(smem_raw + 32768) + cur * 8192;
#pragma unroll
        for (int ks = 0; ks < 2; ks++) {
            h8 a[4], b[4];
#pragma unroll
            for (int mt = 0; mt < 4; mt++) {
                int row = wm * 64 + mt * 16 + lr;
                a[mt] = *(const h8*)&Ab[row * 64 + ((ks * 4 + lg) ^ (lr & 7)) * 8];
            }
#pragma unroll
            for (int nt = 0; nt < 4; nt++) {
                int row = wn * 64 + nt * 16 + lr;
                b[nt] = *(const h8*)&Bb[row * 64 + ((ks * 4 + lg) ^ (lr & 7)) * 8];
            }
#pragma unroll
            for (int mt = 0; mt < 4; mt++)
#pragma unroll
                for (int nt = 0; nt < 4; nt++)
                    acc[mt][nt] = __builtin_amdgcn_mfma_f32_16x16x32_f16(a[mt], b[nt], acc[mt][nt], 0, 0, 0);
        }
        __builtin_amdgcn_sched_barrier(0);     // pin: ds_reads not sunk below
        __builtin_amdgcn_s_barrier();          // done reading buf cur (t+1 overwrites it)
        cur ^= 1;
    }

    const int b_ = m0 >> 11;
    const int mloc = m0 & (NT - 1);

    if (ni < 8) {
        // ---- q tile: stage f16 (pre-scaled) into Tq, stream out coalesced ----
        __syncthreads();   // all waves done with LDS bufs
#pragma unroll
        for (int mt = 0; mt < 4; mt++)
#pragma unroll
            for (int nt = 0; nt < 4; nt++)
#pragma unroll
                for (int r = 0; r < 4; r++)
                    Tq[wn][wm * 64 + mt * 16 + lg * 4 + r][nt * 16 + lr] =
                        (_Float16)(acc[mt][nt][r] * SCALE_Q);
        __syncthreads();
        const int h0 = n0 >> 6;
#pragma unroll
        for (int i = 0; i < 8; i++) {
            int id = i * 256 + tid;                  // 0..2047 chunks of 16B
            int hh = id >> 10, rem = id & 1023;
            int t = rem >> 3, dk8 = (rem & 7) * 8;
            h8 v = *(const h8*)&Tq[hh][t][dk8];
            *(h8*)&qh[((size_t)(b_ * NH + h0 + hh) * NT + mloc + t) * DKK + dk8] = v;
        }
    } else if (ni < 16) {
        // ---- k tile: f32 out_k direct + kh staged via Tq (coalesced) ----
        __syncthreads();
#pragma unroll
        for (int mt = 0; mt < 4; mt++)
#pragma unroll
            for (int nt = 0; nt < 4; nt++)
#pragma unroll
                for (int r = 0; r < 4; r++) {
                    int t = wm * 64 + mt * 16 + lg * 4 + r;
                    int g2 = n0 - 1024 + wn * 64 + nt * 16 + lr;
                    float v = acc[mt][nt][r];
                    int h = g2 >> 6, dk = g2 & 63;
                    out_k[((size_t)(b_ * NH + h) * KV + OFF + mloc + t) * DKK + dk] = v;
                    Tq[wn][t][nt * 16 + lr] = (_Float16)v;
                }
        __syncthreads();
        const int h0 = (n0 - 1024) >> 6;
#pragma unroll
        for (int i = 0; i < 8; i++) {
            int id = i * 256 + tid;
            int hh = id >> 10, rem = id & 1023;
            int t = rem >> 3, dk8 = (rem & 7) * 8;
            h8 v = *(const h8*)&Tq[hh][t][dk8];
            *(h8*)&kh[((size_t)(b_ * NH + h0 + hh) * KV + OFF + mloc + t) * DKK + dk8] = v;
        }
    } else {
        // ---- v tile: f32 out_v + vTh via LDS transpose ----
        __syncthreads();
#pragma unroll
        for (int mt = 0; mt < 4; mt++)
#pragma unroll
            for (int nt = 0; nt < 4; nt++) {
                h4 ph;
#pragma unroll
                for (int r = 0; r < 4; r++) {
                    int grow = m0 + wm * 64 + mt * 16 + lg * 4 + r;
                    int gcol = n0 - 2048 + wn * 64 + nt * 16 + lr;
                    float v = acc[mt][nt][r];
                    int bb = grow >> 11, t = grow & (NT - 1);
                    int h = gcol / DV;
                    int c = gcol - h * DV;
                    out_v[((size_t)(bb * NH + h) * KV + OFF + t) * DVP + c] = v;
                    ph[r] = (_Float16)v;
                }
                *(h4*)&Ts[w][nt * 16 + lr][mt * 16 + lg * 4] = ph;
            }
        __syncthreads();
        {
            _Float16* vout = vTh + ((size_t)b_ * (NH * DV) + (n0 - 2048)) * KV + OFF + mloc;
            const int seg = tid & 31;
            const int rr = tid >> 5;
#pragma unroll
            for (int i = 0; i < 16; i++) {
                int c = i * 8 + rr;
                int buf = ((seg >> 4) << 1) | (c >> 6);
                h4 vv = *(const h4*)&Ts[buf][c & 63][(seg & 15) * 4];
                *(h4*)&vout[(size_t)c * KV + seg * 4] = vv;
            }
        }
    }
}

// ---------------- flash attention + head-sum (R9/R6 structure) ----------------
// Block = 4 waves sharing one staged K/V tile; wave w handles qt = gq*4+w.
// Fixed-max softmax in log2 domain (q pre-scaled). grid 1024 = 32 gq (desc)
// x 32 bh (XCD-affine).
__global__ __launch_bounds__(256, 4)
void k_attn(const _Float16* __restrict__ qh, const _Float16* __restrict__ kh,
            const _Float16* __restrict__ vTh, float* __restrict__ rot) {
    __shared__ _Float16 Ks[64][64];      // 8 KB  (swizzled)
    __shared__ _Float16 Vs[176][64];     // 22 KB (swizzled, V^T)
    __shared__ _Float16 Ps[4][16][72];   // 9.2 KB per-wave P
    const int tid = threadIdx.x, lane = tid & 63, w = tid >> 6;
    const int lr = lane & 15, lg = lane >> 4;
    const int n = blockIdx.x;
    const int gq = 31 - (n >> 5);                  // LPT: long first
    const int bh = (n & 7) + 8 * ((n >> 3) & 3);   // bh%8 == n%8 (XCD)
    const int b_ = bh >> 4;
    const int qt = gq * 4 + w;
    const int q = qt * 16 + lr;                    // this lane's softmax row

    const _Float16* qp = qh + ((size_t)bh * NT + q) * DKK;
    h8 bq0 = *(const h8*)(qp + lg * 8);
    h8 bq1 = *(const h8*)(qp + 32 + lg * 8);

    const _Float16* kbase = kh + (size_t)bh * KV * DKK;
    const _Float16* vbase = vTh + (size_t)bh * DV * KV;

    f4 o[11];
#pragma unroll
    for (int i = 0; i < 11; i++) o[i] = (f4){0.f, 0.f, 0.f, 0.f};
    float l_acc = 0.f;

    const int nkt = gq + 2;
    const int srow = lane >> 3, sslot = lane & 7;
    const int sc16 = sslot ^ srow;                 // pre-swizzled global col

    for (int kt = 0; kt < nkt; kt++) {
        __syncthreads();                            // everyone done reading prev tile
#pragma unroll
        for (int j = 0; j < 2; j++) {
            int i = w * 2 + j;
            int row = i * 8 + srow;
            load_lds16(&kbase[(size_t)(kt * 64 + row) * DKK + sc16 * 8],
                       (_Float16*)Ks + i * 512);
        }
#pragma unroll
        for (int j = 0; j < 6; j++) {
            int i = w * 6 + j;
            if (i < 22) {
                int row = i * 8 + srow;
                load_lds16(&vbase[(size_t)row * KV + kt * 64 + sc16 * 8],
                           (_Float16*)Vs + i * 512);
            }
        }
        asm volatile("s_waitcnt vmcnt(0)" ::: "memory");
        __syncthreads();                            // tile visible to all

        f4 s[4];
#pragma unroll
        for (int nt = 0; nt < 4; nt++) {
            int krow = nt * 16 + lr;
            h8 ak0 = *(const h8*)&Ks[krow][(lg ^ (lr & 7)) * 8];
            h8 ak1 = *(const h8*)&Ks[krow][((4 + lg) ^ (lr & 7)) * 8];
            f4 st = (f4){0.f, 0.f, 0.f, 0.f};
            st = __builtin_amdgcn_mfma_f32_16x16x32_f16(ak0, bq0, st, 0, 0, 0);
            st = __builtin_amdgcn_mfma_f32_16x16x32_f16(ak1, bq1, st, 0, 0, 0);
            s[nt] = st;
        }

#pragma unroll
        for (int nt = 0; nt < 4; nt++) {
            h4 ph;
#pragma unroll
            for (int r = 0; r < 4; r++) {
                int key = kt * 64 + nt * 16 + lg * 4 + r;
                float sv = fminf(s[nt][r], CLAMP_S);
                float p = (key <= q + OFF) ? __builtin_exp2f(sv) : 0.f;
                l_acc += p;
                ph[r] = (_Float16)p;
            }
            *(h4*)&Ps[w][lr][nt * 16 + lg * 4] = ph;
        }

#pragma unroll
        for (int ks = 0; ks < 2; ks++) {
            h8 ap = *(const h8*)&Ps[w][lr][ks * 32 + lg * 8];
#pragma unroll
            for (int nt = 0; nt < 11; nt++) {
                int vrow = nt * 16 + lr;
                h8 bv = *(const h8*)&Vs[vrow][((ks * 4 + lg) ^ (lr & 7)) * 8];
                o[nt] = __builtin_amdgcn_mfma_f32_16x16x32_f16(ap, bv, o[nt], 0, 0, 0);
            }
        }
    }

    l_acc += __shfl_xor(l_acc, 16);
    l_acc += __shfl_xor(l_acc, 32);
    float lq[4];
#pragma unroll
    for (int r = 0; r < 4; r++) lq[r] = 1.f / __shfl(l_acc, lg * 4 + r);
#pragma unroll
    for (int r = 0; r < 4; r++) {
        int t = qt * 16 + lg * 4 + r;
#pragma unroll
        for (int nt = 0; nt < 11; nt++) {
            atomicAdd(&rot[((size_t)b_ * NT + t) * DV + nt * 16 + lr], o[nt][r] * lq[r]);
        }
    }
}

// ---------------- per-token Kronecker rotation via expm ----------------
__device__ __forceinline__ int triu16(int r, int c) { return r * 15 - (r * (r - 1)) / 2 + (c - r - 1); }
__device__ __forceinline__ int triu8(int r, int c)  { return r * 7  - (r * (r - 1)) / 2 + (c - r - 1); }

__global__ __launch_bounds__(64)
void k_rotate(const float* __restrict__ x, const float* __restrict__ rot,
              float* __restrict__ y) {
    __shared__ float A16[16][16], Ta[16][16], Tb[16][16];
    __shared__ float A8[2][8][8], T8a[2][8][8], T8b[2][8][8];
    __shared__ float pbuf[176];
    __shared__ float xt[1024], t1[1024], t2[1024];
    const int tok = blockIdx.x;
    const int lane = threadIdx.x;

    for (int i = lane; i < 176; i += 64) pbuf[i] = rot[(size_t)tok * DV + i];
    for (int i = lane; i < 1024; i += 64) xt[i] = x[(size_t)tok * NC + i];
    __syncthreads();

#pragma unroll
    for (int j = 0; j < 4; j++) {
        int e = lane * 4 + j, r = e >> 4, c = e & 15;
        float v = 0.f;
        if (r < c) v = pbuf[triu16(r, c)];
        else if (r > c) v = -pbuf[triu16(c, r)];
        A16[r][c] = v;
    }
    {
        int r = lane >> 3, c = lane & 7;
#pragma unroll
        for (int m = 0; m < 2; m++) {
            float v = 0.f;
            if (r < c) v = pbuf[120 + m * 28 + triu8(r, c)];
            else if (r > c) v = -pbuf[120 + m * 28 + triu8(c, r)];
            A8[m][r][c] = v;
        }
    }
    __syncthreads();

    float rn = 0.f;
    if (lane < 16) {
#pragma unroll
        for (int c = 0; c < 16; c++) rn += fabsf(A16[lane][c]);
    }
#pragma unroll
    for (int mm = 1; mm < 16; mm <<= 1) rn = fmaxf(rn, __shfl_xor(rn, mm));
    rn = __shfl(rn, 0);
    int s = 0;
    while (rn > 0.5f && s < 60) { rn *= 0.5f; s++; }
    const float sc16 = exp2f((float)(-s));
    __syncthreads();
#pragma unroll
    for (int j = 0; j < 4; j++) { int e = lane * 4 + j; A16[e >> 4][e & 15] *= sc16; }
    __syncthreads();
#pragma unroll
    for (int j = 0; j < 4; j++) {
        int e = lane * 4 + j, r = e >> 4, c = e & 15;
        Ta[r][c] = (r == c ? 1.f : 0.f) + A16[r][c] * (1.f / 12.f);
    }
    __syncthreads();
    float (*Tc)[16] = Ta, (*Tn)[16] = Tb;
    for (int k = 11; k >= 1; k--) {
#pragma unroll
        for (int j = 0; j < 4; j++) {
            int e = lane * 4 + j, r = e >> 4, c = e & 15;
            float acc = 0.f;
#pragma unroll
            for (int q = 0; q < 16; q++) acc += A16[r][q] * Tc[q][c];
            Tn[r][c] = acc * (1.f / (float)k) + (r == c ? 1.f : 0.f);
        }
        __syncthreads();
        float (*tmp)[16] = Tc; Tc = Tn; Tn = tmp;
    }
    for (int it = 0; it < s; it++) {
#pragma unroll
        for (int j = 0; j < 4; j++) {
            int e = lane * 4 + j, r = e >> 4, c = e & 15;
            float acc = 0.f;
#pragma unroll
            for (int q = 0; q < 16; q++) acc += Tc[r][q] * Tc[q][c];
            Tn[r][c] = acc;
        }
        __syncthreads();
        float (*tmp)[16] = Tc; Tc = Tn; Tn = tmp;
    }

    float (*R2p)[8] = T8a[0];
    float (*R3p)[8] = T8a[1];
    {
        int r = lane >> 3, c = lane & 7;
        for (int m = 0; m < 2; m++) {
            float rn8 = 0.f;
            if (lane < 8) {
#pragma unroll
                for (int cc = 0; cc < 8; cc++) rn8 += fabsf(A8[m][lane][cc]);
            }
#pragma unroll
            for (int mm = 1; mm < 8; mm <<= 1) rn8 = fmaxf(rn8, __shfl_xor(rn8, mm));
            rn8 = __shfl(rn8, 0);
            int s8 = 0;
            while (rn8 > 0.5f && s8 < 60) { rn8 *= 0.5f; s8++; }
            float sc8 = exp2f((float)(-s8));
            __syncthreads();
            A8[m][r][c] *= sc8;
            __syncthreads();
            T8a[m][r][c] = (r == c ? 1.f : 0.f) + A8[m][r][c] * (1.f / 12.f);
            __syncthreads();
            float (*tc)[8] = T8a[m], (*tn)[8] = T8b[m];
            for (int k = 11; k >= 1; k--) {
                float acc = 0.f;
#pragma unroll
                for (int q = 0; q < 8; q++) acc += A8[m][r][q] * tc[q][c];
                tn[r][c] = acc * (1.f / (float)k) + (r == c ? 1.f : 0.f);
                __syncthreads();
                float (*tmp)[8] = tc; tc = tn; tn = tmp;
            }
            for (int it = 0; it < s8; it++) {
                float acc = 0.f;
#pragma unroll
                for (int q = 0; q < 8; q++) acc += tc[r][q] * tc[q][c];
                tn[r][c] = acc;
                __syncthreads();
                float (*tmp)[8] = tc; tc = tn; tn = tmp;
            }
            if (m == 0) R2p = tc; else R3p = tc;
        }
    }
    __syncthreads();

    for (int o = lane; o < 1024; o += 64) {
        int c = o & 7, base = o & ~7;
        float acc = 0.f;
#pragma unroll
        for (int j = 0; j < 8; j++) acc += R3p[c][j] * xt[base + j];
        t1[o] = acc;
    }
    __syncthreads();
    for (int o = lane; o < 1024; o += 64) {
        int c = o & 7, bb = (o >> 3) & 7, a = o >> 6;
        float acc = 0.f;
#pragma unroll
        for (int j = 0; j < 8; j++) acc += R2p[bb][j] * t1[a * 64 + j * 8 + c];
        t2[o] = acc;
    }
    __syncthreads();
    for (int o = lane; o < 1024; o += 64) {
        int rr = o & 63, a = o >> 6;
        float acc = 0.f;
#pragma unroll
        for (int j = 0; j < 16; j++) acc += Tc[a][j] * t2[j * 64 + rr];
        y[(size_t)tok * NC + o] = acc;
    }
}

// ---------------- launcher ----------------
extern "C" void kernel_launch(void* const* d_in, const int* in_sizes, int n_in,
                              void* d_out, int out_size, void* d_ws, size_t ws_size,
                              hipStream_t stream) {
    const float* x   = (const float*)d_in[0];
    const float* ck  = (const float*)d_in[1];
    const float* cv  = (const float*)d_in[2];
    const float* wqk = (const float*)d_in[3];
    const float* wv  = (const float*)d_in[4];

    float* out_y = (float*)d_out;
    float* out_k = out_y + (size_t)NB * NT * NC;
    float* out_v = out_k + (size_t)NB * NH * KV * DKK;

    char* ws = (char*)d_ws;
    _Float16* xh   = (_Float16*)ws;  ws += (size_t)NB * NT * NC * 2;
    _Float16* wqkh = (_Float16*)ws;  ws += (size_t)2 * NH * DKK * NC * 2;   // contiguous with wvh
    _Float16* wvh  = (_Float16*)ws;  ws += (size_t)NH * DV * NC * 2;
    _Float16* qh   = (_Float16*)ws;  ws += (size_t)NB * NH * NT * DKK * 2;
    _Float16* kh   = (_Float16*)ws;  ws += (size_t)NB * NH * KV * DKK * 2;
    _Float16* vTh  = (_Float16*)ws;  ws += (size_t)NB * NH * DV * KV * 2;
    float*    rotb = (float*)ws;     ws += (size_t)NB * NT * DV * 4;

    k_prep_a<<<dim3((PREPA_END + 255) / 256), dim3(256), 0, stream>>>(
        x, wqk, wv, xh, wqkh, wvh, rotb);
    k_prep_b<<<dim3((PREPB_END + 255) / 256), dim3(256), 0, stream>>>(
        ck, cv, out_k, kh, out_v, vTh);

    k_gemm_fused<<<dim3(1216), dim3(256), 0, stream>>>(xh, wqkh, qh, kh, out_k, vTh, out_v);

    k_attn<<<dim3(1024), dim3(256), 0, stream>>>(qh, kh, vTh, rotb);

    k_rotate<<<dim3(NB * NT), dim3(64), 0, stream>>>(x, rotb, out_y);
}

// Round 13
// 185.410 us; speedup vs baseline: 1.1012x; 1.0331x over previous
//
#include <hip/hip_runtime.h>

typedef _Float16 h8 __attribute__((ext_vector_type(8)));
typedef _Float16 h4 __attribute__((ext_vector_type(4)));
typedef float f4 __attribute__((ext_vector_type(4)));

#define NB 2
#define NT 2048
#define NC 1024
#define NH 16
#define DKK 64
#define DV 176
#define DVP 256
#define OFF 64
#define KV 2112   // OFF + NT
#define SCALE_Q 0.18033688011112f   // log2(e)/8, folded into q
#define CLAMP_S 11.541560327111f    // 8*log2(e)

__device__ __forceinline__ void load_lds16(const _Float16* g, _Float16* l) {
    __builtin_amdgcn_global_load_lds(
        (const __attribute__((address_space(1))) void*)g,
        (__attribute__((address_space(3))) void*)l, 16, 0, 0);
}

// ---------------- fused prep A: f32->f16 casts + rotb zero ----------------
#define PREPA_X   1048576
#define PREPA_QK  1572864   // + 524288
#define PREPA_WV  2293760   // + 720896
#define PREPA_END 2473984   // + 180224
__global__ __launch_bounds__(256)
void k_prep_a(const float* __restrict__ x, const float* __restrict__ wqk,
              const float* __restrict__ wv, _Float16* __restrict__ xh,
              _Float16* __restrict__ wqkh, _Float16* __restrict__ wvh,
              float* __restrict__ rotb) {
    int i = blockIdx.x * 256 + threadIdx.x;
    if (i >= PREPA_END) return;
    if (i < PREPA_X) {
        float4 v = *(const float4*)(x + (size_t)i * 4);
        h4 h = {(_Float16)v.x, (_Float16)v.y, (_Float16)v.z, (_Float16)v.w};
        *(h4*)(xh + (size_t)i * 4) = h;
    } else if (i < PREPA_QK) {
        int j = i - PREPA_X;
        float4 v = *(const float4*)(wqk + (size_t)j * 4);
        h4 h = {(_Float16)v.x, (_Float16)v.y, (_Float16)v.z, (_Float16)v.w};
        *(h4*)(wqkh + (size_t)j * 4) = h;
    } else if (i < PREPA_WV) {
        int j = i - PREPA_QK;
        float4 v = *(const float4*)(wv + (size_t)j * 4);
        h4 h = {(_Float16)v.x, (_Float16)v.y, (_Float16)v.z, (_Float16)v.w};
        *(h4*)(wvh + (size_t)j * 4) = h;
    } else {
        int j = i - PREPA_WV;
        *(float4*)(rotb + (size_t)j * 4) = (float4){0.f, 0.f, 0.f, 0.f};
    }
}

// ---------------- fused prep B: KV-cache copies + V pad ----------------
#define PREPB_CK   32768
#define PREPB_CV   163840    // + 131072
#define PREPB_END  1474560   // + 1310720
__global__ __launch_bounds__(256)
void k_prep_b(const float* __restrict__ ck, const float* __restrict__ cv,
              float* __restrict__ out_k, _Float16* __restrict__ kh,
              float* __restrict__ out_v, _Float16* __restrict__ vTh) {
    int i = blockIdx.x * 256 + threadIdx.x;
    if (i >= PREPB_END) return;
    if (i < PREPB_CK) {
        int bh = i >> 10, rem = i & 1023;
        int pos = rem >> 4, d4 = (rem & 15) * 4;
        float4 v = *(const float4*)(ck + (size_t)i * 4);
        size_t o = ((size_t)bh * KV + pos) * DKK + d4;
        *(float4*)(out_k + o) = v;
        h4 h = {(_Float16)v.x, (_Float16)v.y, (_Float16)v.z, (_Float16)v.w};
        *(h4*)(kh + o) = h;
    } else if (i < PREPB_CV) {
        int j = i - PREPB_CK;
        int bh = j >> 12, rem = j & 4095;
        int pos = rem >> 6, c4 = (rem & 63) * 4;
        float4 v = *(const float4*)(cv + (size_t)j * 4);
        *(float4*)(out_v + ((size_t)bh * KV + pos) * DVP + c4) = v;
        if (c4 < DV) {
            _Float16* vt = vTh + ((size_t)bh * DV + c4) * KV + pos;
            vt[0]              = (_Float16)v.x;
            vt[KV]             = (_Float16)v.y;
            vt[2 * (size_t)KV] = (_Float16)v.z;
            vt[3 * (size_t)KV] = (_Float16)v.w;
        }
    } else {
        int j = i - PREPB_CV;
        int bh = j / 40960, rem = j - bh * 40960;
        int t = rem / 20, c4 = DV + (rem - t * 20) * 4;
        *(float4*)(out_v + ((size_t)bh * KV + OFF + t) * DVP + c4) = (float4){0.f, 0.f, 0.f, 0.f};
    }
}

// ---------------- fused GEMM: [q|k|v] = x @ W^T ----------------
// BK=64, double-buffered, counted vmcnt(8) + raw s_barrier + sched_barrier
// pins (R12, verified). setprio(1) around MFMA cluster added.
__global__ __launch_bounds__(256)
void k_gemm_fused(const _Float16* __restrict__ xh, const _Float16* __restrict__ wh,
                  _Float16* __restrict__ qh, _Float16* __restrict__ kh,
                  float* __restrict__ out_k, _Float16* __restrict__ vTh,
                  float* __restrict__ out_v) {
    __shared__ char smem_raw[65536];
    auto Ts = (_Float16(*)[64][72])smem_raw;           // [4][64][72] (v epilogue)
    auto Tq = (_Float16(*)[128][68])smem_raw;          // [2][128][68] (q/k epilogue)

    const int tid = threadIdx.x;
    const int lane = tid & 63, w = tid >> 6;
    const int lr = lane & 15, lg = lane >> 4;
    const int wm = w >> 1, wn = w & 1;
    const int n = blockIdx.x, x = n & 7, idx = n >> 3;
    const int mi = (x & 3) * 8 + idx / 19;
    const int ni = (x >> 2) * 19 + idx % 19;
    const int m0 = mi * 128, n0 = ni * 128;
    const int srow = lane >> 3;
    const int sc16 = (lane & 7) ^ srow;

    f4 acc[4][4];
#pragma unroll
    for (int i = 0; i < 4; i++)
#pragma unroll
        for (int j = 0; j < 4; j++) acc[i][j] = (f4){0.f, 0.f, 0.f, 0.f};

    auto stage = [&](int buf, int k0) {
        _Float16* Ab = (_Float16*)smem_raw + buf * 8192;
        _Float16* Bb = (_Float16*)(smem_raw + 32768) + buf * 8192;
#pragma unroll
        for (int j = 0; j < 4; j++) {
            int i = w * 4 + j;
            int row = i * 8 + srow;
            load_lds16(&xh[(size_t)(m0 + row) * NC + k0 + sc16 * 8], Ab + i * 512);
            load_lds16(&wh[(size_t)(n0 + row) * NC + k0 + sc16 * 8], Bb + i * 512);
        }
    };

    stage(0, 0);
    int cur = 0;
    for (int t = 0; t < 16; ++t) {
        if (t < 15) {
            stage(cur ^ 1, (t + 1) * 64);
            asm volatile("s_waitcnt vmcnt(8)" ::: "memory");  // own stage(t) done
        } else {
            asm volatile("s_waitcnt vmcnt(0)" ::: "memory");
        }
        __builtin_amdgcn_s_barrier();          // all waves' stage(t) in LDS
        __builtin_amdgcn_sched_barrier(0);     // pin: no ds_read above barrier

        const _Float16* Ab = (const _Float16*)smem_raw + cur * 8192;
        const _Float16* Bb = (const _Float16*)(smem_raw + 32768) + cur * 8192;
#pragma unroll
        for (int ks = 0; ks < 2; ks++) {
            h8 a[4], b[4];
#pragma unroll
            for (int mt = 0; mt < 4; mt++) {
                int row = wm * 64 + mt * 16 + lr;
                a[mt] = *(const h8*)&Ab[row * 64 + ((ks * 4 + lg) ^ (lr & 7)) * 8];
            }
#pragma unroll
            for (int nt = 0; nt < 4; nt++) {
                int row = wn * 64 + nt * 16 + lr;
                b[nt] = *(const h8*)&Bb[row * 64 + ((ks * 4 + lg) ^ (lr & 7)) * 8];
            }
            __builtin_amdgcn_s_setprio(1);
#pragma unroll
            for (int mt = 0; mt < 4; mt++)
#pragma unroll
                for (int nt = 0; nt < 4; nt++)
                    acc[mt][nt] = __builtin_amdgcn_mfma_f32_16x16x32_f16(a[mt], b[nt], acc[mt][nt], 0, 0, 0);
            __builtin_amdgcn_s_setprio(0);
        }
        __builtin_amdgcn_sched_barrier(0);     // pin: ds_reads not sunk below
        __builtin_amdgcn_s_barrier();          // done reading buf cur
        cur ^= 1;
    }

    const int b_ = m0 >> 11;
    const int mloc = m0 & (NT - 1);

    if (ni < 8) {
        __syncthreads();
#pragma unroll
        for (int mt = 0; mt < 4; mt++)
#pragma unroll
            for (int nt = 0; nt < 4; nt++)
#pragma unroll
                for (int r = 0; r < 4; r++)
                    Tq[wn][wm * 64 + mt * 16 + lg * 4 + r][nt * 16 + lr] =
                        (_Float16)(acc[mt][nt][r] * SCALE_Q);
        __syncthreads();
        const int h0 = n0 >> 6;
#pragma unroll
        for (int i = 0; i < 8; i++) {
            int id = i * 256 + tid;
            int hh = id >> 10, rem = id & 1023;
            int t = rem >> 3, dk8 = (rem & 7) * 8;
            h8 v = *(const h8*)&Tq[hh][t][dk8];
            *(h8*)&qh[((size_t)(b_ * NH + h0 + hh) * NT + mloc + t) * DKK + dk8] = v;
        }
    } else if (ni < 16) {
        __syncthreads();
#pragma unroll
        for (int mt = 0; mt < 4; mt++)
#pragma unroll
            for (int nt = 0; nt < 4; nt++)
#pragma unroll
                for (int r = 0; r < 4; r++) {
                    int t = wm * 64 + mt * 16 + lg * 4 + r;
                    int g2 = n0 - 1024 + wn * 64 + nt * 16 + lr;
                    float v = acc[mt][nt][r];
                    int h = g2 >> 6, dk = g2 & 63;
                    out_k[((size_t)(b_ * NH + h) * KV + OFF + mloc + t) * DKK + dk] = v;
                    Tq[wn][t][nt * 16 + lr] = (_Float16)v;
                }
        __syncthreads();
        const int h0 = (n0 - 1024) >> 6;
#pragma unroll
        for (int i = 0; i < 8; i++) {
            int id = i * 256 + tid;
            int hh = id >> 10, rem = id & 1023;
            int t = rem >> 3, dk8 = (rem & 7) * 8;
            h8 v = *(const h8*)&Tq[hh][t][dk8];
            *(h8*)&kh[((size_t)(b_ * NH + h0 + hh) * KV + OFF + mloc + t) * DKK + dk8] = v;
        }
    } else {
        __syncthreads();
#pragma unroll
        for (int mt = 0; mt < 4; mt++)
#pragma unroll
            for (int nt = 0; nt < 4; nt++) {
                h4 ph;
#pragma unroll
                for (int r = 0; r < 4; r++) {
                    int grow = m0 + wm * 64 + mt * 16 + lg * 4 + r;
                    int gcol = n0 - 2048 + wn * 64 + nt * 16 + lr;
                    float v = acc[mt][nt][r];
                    int bb = grow >> 11, t = grow & (NT - 1);
                    int h = gcol / DV;
                    int c = gcol - h * DV;
                    out_v[((size_t)(bb * NH + h) * KV + OFF + t) * DVP + c] = v;
                    ph[r] = (_Float16)v;
                }
                *(h4*)&Ts[w][nt * 16 + lr][mt * 16 + lg * 4] = ph;
            }
        __syncthreads();
        {
            _Float16* vout = vTh + ((size_t)b_ * (NH * DV) + (n0 - 2048)) * KV + OFF + mloc;
            const int seg = tid & 31;
            const int rr = tid >> 5;
#pragma unroll
            for (int i = 0; i < 16; i++) {
                int c = i * 8 + rr;
                int buf = ((seg >> 4) << 1) | (c >> 6);
                h4 vv = *(const h4*)&Ts[buf][c & 63][(seg & 15) * 4];
                *(h4*)&vout[(size_t)c * KV + seg * 4] = vv;
            }
        }
    }
}

// ---------------- flash attention + head-sum ----------------
// R6 structure + MASK PEEL: tiles kt <= gq are provably unmasked
// (max key = 64gq+63 < min(q)+OFF = 64gq+64), so the compare/cndmask runs
// only on the final tile. setprio(1) wraps the MFMA clusters (m191: attn+).
__global__ __launch_bounds__(256, 4)
void k_attn(const _Float16* __restrict__ qh, const _Float16* __restrict__ kh,
            const _Float16* __restrict__ vTh, float* __restrict__ rot) {
    __shared__ _Float16 Ks[64][64];      // 8 KB  (swizzled)
    __shared__ _Float16 Vs[176][64];     // 22 KB (swizzled, V^T)
    __shared__ _Float16 Ps[4][16][72];   // 9.2 KB per-wave P
    const int tid = threadIdx.x, lane = tid & 63, w = tid >> 6;
    const int lr = lane & 15, lg = lane >> 4;
    const int n = blockIdx.x;
    const int gq = 31 - (n >> 5);                  // LPT: long first
    const int bh = (n & 7) + 8 * ((n >> 3) & 3);   // bh%8 == n%8 (XCD)
    const int b_ = bh >> 4;
    const int qt = gq * 4 + w;
    const int q = qt * 16 + lr;                    // this lane's softmax row

    const _Float16* qp = qh + ((size_t)bh * NT + q) * DKK;
    h8 bq0 = *(const h8*)(qp + lg * 8);
    h8 bq1 = *(const h8*)(qp + 32 + lg * 8);

    const _Float16* kbase = kh + (size_t)bh * KV * DKK;
    const _Float16* vbase = vTh + (size_t)bh * DV * KV;

    f4 o[11];
#pragma unroll
    for (int i = 0; i < 11; i++) o[i] = (f4){0.f, 0.f, 0.f, 0.f};
    float l_acc = 0.f;

    const int nkt = gq + 2;
    const int srow = lane >> 3, sslot = lane & 7;
    const int sc16 = sslot ^ srow;                 // pre-swizzled global col

    for (int kt = 0; kt < nkt; kt++) {
        __syncthreads();                            // everyone done reading prev tile
#pragma unroll
        for (int j = 0; j < 2; j++) {
            int i = w * 2 + j;
            int row = i * 8 + srow;
            load_lds16(&kbase[(size_t)(kt * 64 + row) * DKK + sc16 * 8],
                       (_Float16*)Ks + i * 512);
        }
#pragma unroll
        for (int j = 0; j < 6; j++) {
            int i = w * 6 + j;
            if (i < 22) {
                int row = i * 8 + srow;
                load_lds16(&vbase[(size_t)row * KV + kt * 64 + sc16 * 8],
                           (_Float16*)Vs + i * 512);
            }
        }
        asm volatile("s_waitcnt vmcnt(0)" ::: "memory");
        __syncthreads();                            // tile visible to all

        f4 s[4];
        __builtin_amdgcn_s_setprio(1);
#pragma unroll
        for (int nt = 0; nt < 4; nt++) {
            int krow = nt * 16 + lr;
            h8 ak0 = *(const h8*)&Ks[krow][(lg ^ (lr & 7)) * 8];
            h8 ak1 = *(const h8*)&Ks[krow][((4 + lg) ^ (lr & 7)) * 8];
            f4 st = (f4){0.f, 0.f, 0.f, 0.f};
            st = __builtin_amdgcn_mfma_f32_16x16x32_f16(ak0, bq0, st, 0, 0, 0);
            st = __builtin_amdgcn_mfma_f32_16x16x32_f16(ak1, bq1, st, 0, 0, 0);
            s[nt] = st;
        }
        __builtin_amdgcn_s_setprio(0);

        if (kt + 1 < nkt) {
            // unmasked tiles (kt <= gq): no key computation, no cndmask
#pragma unroll
            for (int nt = 0; nt < 4; nt++) {
                h4 ph;
#pragma unroll
                for (int r = 0; r < 4; r++) {
                    float p = __builtin_exp2f(fminf(s[nt][r], CLAMP_S));
                    l_acc += p;
                    ph[r] = (_Float16)p;
                }
                *(h4*)&Ps[w][lr][nt * 16 + lg * 4] = ph;
            }
        } else {
            // final tile: causal mask active
#pragma unroll
            for (int nt = 0; nt < 4; nt++) {
                h4 ph;
#pragma unroll
                for (int r = 0; r < 4; r++) {
                    int key = kt * 64 + nt * 16 + lg * 4 + r;
                    float sv = fminf(s[nt][r], CLAMP_S);
                    float p = (key <= q + OFF) ? __builtin_exp2f(sv) : 0.f;
                    l_acc += p;
                    ph[r] = (_Float16)p;
                }
                *(h4*)&Ps[w][lr][nt * 16 + lg * 4] = ph;
            }
        }

        __builtin_amdgcn_s_setprio(1);
#pragma unroll
        for (int ks = 0; ks < 2; ks++) {
            h8 ap = *(const h8*)&Ps[w][lr][ks * 32 + lg * 8];
#pragma unroll
            for (int nt = 0; nt < 11; nt++) {
                int vrow = nt * 16 + lr;
                h8 bv = *(const h8*)&Vs[vrow][((ks * 4 + lg) ^ (lr & 7)) * 8];
                o[nt] = __builtin_amdgcn_mfma_f32_16x16x32_f16(ap, bv, o[nt], 0, 0, 0);
            }
        }
        __builtin_amdgcn_s_setprio(0);
    }

    l_acc += __shfl_xor(l_acc, 16);
    l_acc += __shfl_xor(l_acc, 32);
    float lq[4];
#pragma unroll
    for (int r = 0; r < 4; r++) lq[r] = 1.f / __shfl(l_acc, lg * 4 + r);
#pragma unroll
    for (int r = 0; r < 4; r++) {
        int t = qt * 16 + lg * 4 + r;
#pragma unroll
        for (int nt = 0; nt < 11; nt++) {
            atomicAdd(&rot[((size_t)b_ * NT + t) * DV + nt * 16 + lr], o[nt][r] * lq[r]);
        }
    }
}

// ---------------- per-token Kronecker rotation via expm ----------------
__device__ __forceinline__ int triu16(int r, int c) { return r * 15 - (r * (r - 1)) / 2 + (c - r - 1); }
__device__ __forceinline__ int triu8(int r, int c)  { return r * 7  - (r * (r - 1)) / 2 + (c - r - 1); }

__global__ __launch_bounds__(64)
void k_rotate(const float* __restrict__ x, const float* __restrict__ rot,
              float* __restrict__ y) {
    __shared__ float A16[16][16], Ta[16][16], Tb[16][16];
    __shared__ float A8[2][8][8], T8a[2][8][8], T8b[2][8][8];
    __shared__ float pbuf[176];
    __shared__ float xt[1024], t1[1024], t2[1024];
    const int tok = blockIdx.x;
    const int lane = threadIdx.x;

    for (int i = lane; i < 176; i += 64) pbuf[i] = rot[(size_t)tok * DV + i];
    for (int i = lane; i < 1024; i += 64) xt[i] = x[(size_t)tok * NC + i];
    __syncthreads();

#pragma unroll
    for (int j = 0; j < 4; j++) {
        int e = lane * 4 + j, r = e >> 4, c = e & 15;
        float v = 0.f;
        if (r < c) v = pbuf[triu16(r, c)];
        else if (r > c) v = -pbuf[triu16(c, r)];
        A16[r][c] = v;
    }
    {
        int r = lane >> 3, c = lane & 7;
#pragma unroll
        for (int m = 0; m < 2; m++) {
            float v = 0.f;
            if (r < c) v = pbuf[120 + m * 28 + triu8(r, c)];
            else if (r > c) v = -pbuf[120 + m * 28 + triu8(c, r)];
            A8[m][r][c] = v;
        }
    }
    __syncthreads();

    float rn = 0.f;
    if (lane < 16) {
#pragma unroll
        for (int c = 0; c < 16; c++) rn += fabsf(A16[lane][c]);
    }
#pragma unroll
    for (int mm = 1; mm < 16; mm <<= 1) rn = fmaxf(rn, __shfl_xor(rn, mm));
    rn = __shfl(rn, 0);
    int s = 0;
    while (rn > 0.5f && s < 60) { rn *= 0.5f; s++; }
    const float sc16 = exp2f((float)(-s));
    __syncthreads();
#pragma unroll
    for (int j = 0; j < 4; j++) { int e = lane * 4 + j; A16[e >> 4][e & 15] *= sc16; }
    __syncthreads();
#pragma unroll
    for (int j = 0; j < 4; j++) {
        int e = lane * 4 + j, r = e >> 4, c = e & 15;
        Ta[r][c] = (r == c ? 1.f : 0.f) + A16[r][c] * (1.f / 12.f);
    }
    __syncthreads();
    float (*Tc)[16] = Ta, (*Tn)[16] = Tb;
    for (int k = 11; k >= 1; k--) {
#pragma unroll
        for (int j = 0; j < 4; j++) {
            int e = lane * 4 + j, r = e >> 4, c = e & 15;
            float acc = 0.f;
#pragma unroll
            for (int q = 0; q < 16; q++) acc += A16[r][q] * Tc[q][c];
            Tn[r][c] = acc * (1.f / (float)k) + (r == c ? 1.f : 0.f);
        }
        __syncthreads();
        float (*tmp)[16] = Tc; Tc = Tn; Tn = tmp;
    }
    for (int it = 0; it < s; it++) {
#pragma unroll
        for (int j = 0; j < 4; j++) {
            int e = lane * 4 + j, r = e >> 4, c = e & 15;
            float acc = 0.f;
#pragma unroll
            for (int q = 0; q < 16; q++) acc += Tc[r][q] * Tc[q][c];
            Tn[r][c] = acc;
        }
        __syncthreads();
        float (*tmp)[16] = Tc; Tc = Tn; Tn = tmp;
    }

    float (*R2p)[8] = T8a[0];
    float (*R3p)[8] = T8a[1];
    {
        int r = lane >> 3, c = lane & 7;
        for (int m = 0; m < 2; m++) {
            float rn8 = 0.f;
            if (lane < 8) {
#pragma unroll
                for (int cc = 0; cc < 8; cc++) rn8 += fabsf(A8[m][lane][cc]);
            }
#pragma unroll
            for (int mm = 1; mm < 8; mm <<= 1) rn8 = fmaxf(rn8, __shfl_xor(rn8, mm));
            rn8 = __shfl(rn8, 0);
            int s8 = 0;
            while (rn8 > 0.5f && s8 < 60) { rn8 *= 0.5f; s8++; }
            float sc8 = exp2f((float)(-s8));
            __syncthreads();
            A8[m][r][c] *= sc8;
            __syncthreads();
            T8a[m][r][c] = (r == c ? 1.f : 0.f) + A8[m][r][c] * (1.f / 12.f);
            __syncthreads();
            float (*tc)[8] = T8a[m], (*tn)[8] = T8b[m];
            for (int k = 11; k >= 1; k--) {
                float acc = 0.f;
#pragma unroll
                for (int q = 0; q < 8; q++) acc += A8[m][r][q] * tc[q][c];
                tn[r][c] = acc * (1.f / (float)k) + (r == c ? 1.f : 0.f);
                __syncthreads();
                float (*tmp)[8] = tc; tc = tn; tn = tmp;
            }
            for (int it = 0; it < s8; it++) {
                float acc = 0.f;
#pragma unroll
                for (int q = 0; q < 8; q++) acc += tc[r][q] * tc[q][c];
                tn[r][c] = acc;
                __syncthreads();
                float (*tmp)[8] = tc; tc = tn; tn = tmp;
            }
            if (m == 0) R2p = tc; else R3p = tc;
        }
    }
    __syncthreads();

    for (int o = lane; o < 1024; o += 64) {
        int c = o & 7, base = o & ~7;
        float acc = 0.f;
#pragma unroll
        for (int j = 0; j < 8; j++) acc += R3p[c][j] * xt[base + j];
        t1[o] = acc;
    }
    __syncthreads();
    for (int o = lane; o < 1024; o += 64) {
        int c = o & 7, bb = (o >> 3) & 7, a = o >> 6;
        float acc = 0.f;
#pragma unroll
        for (int j = 0; j < 8; j++) acc += R2p[bb][j] * t1[a * 64 + j * 8 + c];
        t2[o] = acc;
    }
    __syncthreads();
    for (int o = lane; o < 1024; o += 64) {
        int rr = o & 63, a = o >> 6;
        float acc = 0.f;
#pragma unroll
        for (int j = 0; j < 16; j++) acc += Tc[a][j] * t2[j * 64 + rr];
        y[(size_t)tok * NC + o] = acc;
    }
}

// ---------------- launcher ----------------
extern "C" void kernel_launch(void* const* d_in, const int* in_sizes, int n_in,
                              void* d_out, int out_size, void* d_ws, size_t ws_size,
                              hipStream_t stream) {
    const float* x   = (const float*)d_in[0];
    const float* ck  = (const float*)d_in[1];
    const float* cv  = (const float*)d_in[2];
    const float* wqk = (const float*)d_in[3];
    const float* wv  = (const float*)d_in[4];

    float* out_y = (float*)d_out;
    float* out_k = out_y + (size_t)NB * NT * NC;
    float* out_v = out_k + (size_t)NB * NH * KV * DKK;

    char* ws = (char*)d_ws;
    _Float16* xh   = (_Float16*)ws;  ws += (size_t)NB * NT * NC * 2;
    _Float16* wqkh = (_Float16*)ws;  ws += (size_t)2 * NH * DKK * NC * 2;   // contiguous with wvh
    _Float16* wvh  = (_Float16*)ws;  ws += (size_t)NH * DV * NC * 2;
    _Float16* qh   = (_Float16*)ws;  ws += (size_t)NB * NH * NT * DKK * 2;
    _Float16* kh   = (_Float16*)ws;  ws += (size_t)NB * NH * KV * DKK * 2;
    _Float16* vTh  = (_Float16*)ws;  ws += (size_t)NB * NH * DV * KV * 2;
    float*    rotb = (float*)ws;     ws += (size_t)NB * NT * DV * 4;

    k_prep_a<<<dim3((PREPA_END + 255) / 256), dim3(256), 0, stream>>>(
        x, wqk, wv, xh, wqkh, wvh, rotb);
    k_prep_b<<<dim3((PREPB_END + 255) / 256), dim3(256), 0, stream>>>(
        ck, cv, out_k, kh, out_v, vTh);

    k_gemm_fused<<<dim3(1216), dim3(256), 0, stream>>>(xh, wqkh, qh, kh, out_k, vTh, out_v);

    k_attn<<<dim3(1024), dim3(256), 0, stream>>>(qh, kh, vTh, rotb);

    k_rotate<<<dim3(NB * NT), dim3(64), 0, stream>>>(x, rotb, out_y);
}

// Round 14
// 176.100 us; speedup vs baseline: 1.1594x; 1.0529x over previous
//
#include <hip/hip_runtime.h>

typedef _Float16 h8 __attribute__((ext_vector_type(8)));
typedef _Float16 h4 __attribute__((ext_vector_type(4)));
typedef float f4 __attribute__((ext_vector_type(4)));

#define NB 2
#define NT 2048
#define NC 1024
#define NH 16
#define DKK 64
#define DV 176
#define DVP 256
#define OFF 64
#define KV 2112   // OFF + NT
#define SCALE_Q 0.18033688011112f   // log2(e)/8, folded into q
#define CLAMP_S 11.541560327111f    // 8*log2(e)

__device__ __forceinline__ void load_lds16(const _Float16* g, _Float16* l) {
    __builtin_amdgcn_global_load_lds(
        (const __attribute__((address_space(1))) void*)g,
        (__attribute__((address_space(3))) void*)l, 16, 0, 0);
}

// ---------------- fused prep A: f32->f16 casts + rotb zero ----------------
#define PREPA_X   1048576
#define PREPA_QK  1572864   // + 524288
#define PREPA_WV  2293760   // + 720896
#define PREPA_END 2473984   // + 180224
__global__ __launch_bounds__(256)
void k_prep_a(const float* __restrict__ x, const float* __restrict__ wqk,
              const float* __restrict__ wv, _Float16* __restrict__ xh,
              _Float16* __restrict__ wqkh, _Float16* __restrict__ wvh,
              float* __restrict__ rotb) {
    int i = blockIdx.x * 256 + threadIdx.x;
    if (i >= PREPA_END) return;
    if (i < PREPA_X) {
        float4 v = *(const float4*)(x + (size_t)i * 4);
        h4 h = {(_Float16)v.x, (_Float16)v.y, (_Float16)v.z, (_Float16)v.w};
        *(h4*)(xh + (size_t)i * 4) = h;
    } else if (i < PREPA_QK) {
        int j = i - PREPA_X;
        float4 v = *(const float4*)(wqk + (size_t)j * 4);
        h4 h = {(_Float16)v.x, (_Float16)v.y, (_Float16)v.z, (_Float16)v.w};
        *(h4*)(wqkh + (size_t)j * 4) = h;
    } else if (i < PREPA_WV) {
        int j = i - PREPA_QK;
        float4 v = *(const float4*)(wv + (size_t)j * 4);
        h4 h = {(_Float16)v.x, (_Float16)v.y, (_Float16)v.z, (_Float16)v.w};
        *(h4*)(wvh + (size_t)j * 4) = h;
    } else {
        int j = i - PREPA_WV;
        *(float4*)(rotb + (size_t)j * 4) = (float4){0.f, 0.f, 0.f, 0.f};
    }
}

// ---------------- fused prep B: KV-cache copies + V pad ----------------
#define PREPB_CK   32768
#define PREPB_CV   163840    // + 131072
#define PREPB_END  1474560   // + 1310720
__global__ __launch_bounds__(256)
void k_prep_b(const float* __restrict__ ck, const float* __restrict__ cv,
              float* __restrict__ out_k, _Float16* __restrict__ kh,
              float* __restrict__ out_v, _Float16* __restrict__ vTh) {
    int i = blockIdx.x * 256 + threadIdx.x;
    if (i >= PREPB_END) return;
    if (i < PREPB_CK) {
        int bh = i >> 10, rem = i & 1023;
        int pos = rem >> 4, d4 = (rem & 15) * 4;
        float4 v = *(const float4*)(ck + (size_t)i * 4);
        size_t o = ((size_t)bh * KV + pos) * DKK + d4;
        *(float4*)(out_k + o) = v;
        h4 h = {(_Float16)v.x, (_Float16)v.y, (_Float16)v.z, (_Float16)v.w};
        *(h4*)(kh + o) = h;
    } else if (i < PREPB_CV) {
        int j = i - PREPB_CK;
        int bh = j >> 12, rem = j & 4095;
        int pos = rem >> 6, c4 = (rem & 63) * 4;
        float4 v = *(const float4*)(cv + (size_t)j * 4);
        *(float4*)(out_v + ((size_t)bh * KV + pos) * DVP + c4) = v;
        if (c4 < DV) {
            _Float16* vt = vTh + ((size_t)bh * DV + c4) * KV + pos;
            vt[0]              = (_Float16)v.x;
            vt[KV]             = (_Float16)v.y;
            vt[2 * (size_t)KV] = (_Float16)v.z;
            vt[3 * (size_t)KV] = (_Float16)v.w;
        }
    } else {
        int j = i - PREPB_CV;
        int bh = j / 40960, rem = j - bh * 40960;
        int t = rem / 20, c4 = DV + (rem - t * 20) * 4;
        *(float4*)(out_v + ((size_t)bh * KV + OFF + t) * DVP + c4) = (float4){0.f, 0.f, 0.f, 0.f};
    }
}

// ---------------- fused GEMM: [q|k|v] = x @ W^T ----------------
// BK=64, double-buffered, counted vmcnt(8) + raw s_barrier + sched_barrier
// pins + setprio (R12/R13, verified). NEW: L2-WINDOW block ordering — the
// 152 blocks per XCD are walked in 8mi x 8ni windows (2MB A + 2MB B = one
// L2), so the ~64 concurrently-resident blocks per XCD stage from L2 not L3.
__global__ __launch_bounds__(256)
void k_gemm_fused(const _Float16* __restrict__ xh, const _Float16* __restrict__ wh,
                  _Float16* __restrict__ qh, _Float16* __restrict__ kh,
                  float* __restrict__ out_k, _Float16* __restrict__ vTh,
                  float* __restrict__ out_v) {
    __shared__ char smem_raw[65536];
    auto Ts = (_Float16(*)[64][72])smem_raw;           // [4][64][72] (v epilogue)
    auto Tq = (_Float16(*)[128][68])smem_raw;          // [2][128][68] (q/k epilogue)

    const int tid = threadIdx.x;
    const int lane = tid & 63, w = tid >> 6;
    const int lr = lane & 15, lg = lane >> 4;
    const int wm = w >> 1, wn = w & 1;
    const int n = blockIdx.x, x = n & 7, idx = n >> 3;
    // L2-window remap within the XCD's 8mi x 19ni rect (bijective):
    // window c = idx>>6 covers ni_l in [8c, 8c+8) (c=2: 3-wide tail).
    const int c_  = idx >> 6;
    const int loc = idx & 63;
    const int mi = (x & 3) * 8 + (loc & 7);
    const int ni = (x >> 2) * 19 + c_ * 8 + (loc >> 3);
    const int m0 = mi * 128, n0 = ni * 128;
    const int srow = lane >> 3;
    const int sc16 = (lane & 7) ^ srow;

    f4 acc[4][4];
#pragma unroll
    for (int i = 0; i < 4; i++)
#pragma unroll
        for (int j = 0; j < 4; j++) acc[i][j] = (f4){0.f, 0.f, 0.f, 0.f};

    auto stage = [&](int buf, int k0) {
        _Float16* Ab = (_Float16*)smem_raw + buf * 8192;
        _Float16* Bb = (_Float16*)(smem_raw + 32768) + buf * 8192;
#pragma unroll
        for (int j = 0; j < 4; j++) {
            int i = w * 4 + j;
            int row = i * 8 + srow;
            load_lds16(&xh[(size_t)(m0 + row) * NC + k0 + sc16 * 8], Ab + i * 512);
            load_lds16(&wh[(size_t)(n0 + row) * NC + k0 + sc16 * 8], Bb + i * 512);
        }
    };

    stage(0, 0);
    int cur = 0;
    for (int t = 0; t < 16; ++t) {
        if (t < 15) {
            stage(cur ^ 1, (t + 1) * 64);
            asm volatile("s_waitcnt vmcnt(8)" ::: "memory");  // own stage(t) done
        } else {
            asm volatile("s_waitcnt vmcnt(0)" ::: "memory");
        }
        __builtin_amdgcn_s_barrier();          // all waves' stage(t) in LDS
        __builtin_amdgcn_sched_barrier(0);     // pin: no ds_read above barrier

        const _Float16* Ab = (const _Float16*)smem_raw + cur * 8192;
        const _Float16* Bb = (const _Float16*)(smem_raw + 32768) + cur * 8192;
#pragma unroll
        for (int ks = 0; ks < 2; ks++) {
            h8 a[4], b[4];
#pragma unroll
            for (int mt = 0; mt < 4; mt++) {
                int row = wm * 64 + mt * 16 + lr;
                a[mt] = *(const h8*)&Ab[row * 64 + ((ks * 4 + lg) ^ (lr & 7)) * 8];
            }
#pragma unroll
            for (int nt = 0; nt < 4; nt++) {
                int row = wn * 64 + nt * 16 + lr;
                b[nt] = *(const h8*)&Bb[row * 64 + ((ks * 4 + lg) ^ (lr & 7)) * 8];
            }
            __builtin_amdgcn_s_setprio(1);
#pragma unroll
            for (int mt = 0; mt < 4; mt++)
#pragma unroll
                for (int nt = 0; nt < 4; nt++)
                    acc[mt][nt] = __builtin_amdgcn_mfma_f32_16x16x32_f16(a[mt], b[nt], acc[mt][nt], 0, 0, 0);
            __builtin_amdgcn_s_setprio(0);
        }
        __builtin_amdgcn_sched_barrier(0);     // pin: ds_reads not sunk below
        __builtin_amdgcn_s_barrier();          // done reading buf cur
        cur ^= 1;
    }

    const int b_ = m0 >> 11;
    const int mloc = m0 & (NT - 1);

    if (ni < 8) {
        __syncthreads();
#pragma unroll
        for (int mt = 0; mt < 4; mt++)
#pragma unroll
            for (int nt = 0; nt < 4; nt++)
#pragma unroll
                for (int r = 0; r < 4; r++)
                    Tq[wn][wm * 64 + mt * 16 + lg * 4 + r][nt * 16 + lr] =
                        (_Float16)(acc[mt][nt][r] * SCALE_Q);
        __syncthreads();
        const int h0 = n0 >> 6;
#pragma unroll
        for (int i = 0; i < 8; i++) {
            int id = i * 256 + tid;
            int hh = id >> 10, rem = id & 1023;
            int t = rem >> 3, dk8 = (rem & 7) * 8;
            h8 v = *(const h8*)&Tq[hh][t][dk8];
            *(h8*)&qh[((size_t)(b_ * NH + h0 + hh) * NT + mloc + t) * DKK + dk8] = v;
        }
    } else if (ni < 16) {
        __syncthreads();
#pragma unroll
        for (int mt = 0; mt < 4; mt++)
#pragma unroll
            for (int nt = 0; nt < 4; nt++)
#pragma unroll
                for (int r = 0; r < 4; r++) {
                    int t = wm * 64 + mt * 16 + lg * 4 + r;
                    int g2 = n0 - 1024 + wn * 64 + nt * 16 + lr;
                    float v = acc[mt][nt][r];
                    int h = g2 >> 6, dk = g2 & 63;
                    out_k[((size_t)(b_ * NH + h) * KV + OFF + mloc + t) * DKK + dk] = v;
                    Tq[wn][t][nt * 16 + lr] = (_Float16)v;
                }
        __syncthreads();
        const int h0 = (n0 - 1024) >> 6;
#pragma unroll
        for (int i = 0; i < 8; i++) {
            int id = i * 256 + tid;
            int hh = id >> 10, rem = id & 1023;
            int t = rem >> 3, dk8 = (rem & 7) * 8;
            h8 v = *(const h8*)&Tq[hh][t][dk8];
            *(h8*)&kh[((size_t)(b_ * NH + h0 + hh) * KV + OFF + mloc + t) * DKK + dk8] = v;
        }
    } else {
        __syncthreads();
#pragma unroll
        for (int mt = 0; mt < 4; mt++)
#pragma unroll
            for (int nt = 0; nt < 4; nt++) {
                h4 ph;
#pragma unroll
                for (int r = 0; r < 4; r++) {
                    int grow = m0 + wm * 64 + mt * 16 + lg * 4 + r;
                    int gcol = n0 - 2048 + wn * 64 + nt * 16 + lr;
                    float v = acc[mt][nt][r];
                    int bb = grow >> 11, t = grow & (NT - 1);
                    int h = gcol / DV;
                    int c = gcol - h * DV;
                    out_v[((size_t)(bb * NH + h) * KV + OFF + t) * DVP + c] = v;
                    ph[r] = (_Float16)v;
                }
                *(h4*)&Ts[w][nt * 16 + lr][mt * 16 + lg * 4] = ph;
            }
        __syncthreads();
        {
            _Float16* vout = vTh + ((size_t)b_ * (NH * DV) + (n0 - 2048)) * KV + OFF + mloc;
            const int seg = tid & 31;
            const int rr = tid >> 5;
#pragma unroll
            for (int i = 0; i < 16; i++) {
                int c = i * 8 + rr;
                int buf = ((seg >> 4) << 1) | (c >> 6);
                h4 vv = *(const h4*)&Ts[buf][c & 63][(seg & 15) * 4];
                *(h4*)&vout[(size_t)c * KV + seg * 4] = vv;
            }
        }
    }
}

// ---------------- flash attention + head-sum (R13, verified) ----------------
__global__ __launch_bounds__(256, 4)
void k_attn(const _Float16* __restrict__ qh, const _Float16* __restrict__ kh,
            const _Float16* __restrict__ vTh, float* __restrict__ rot) {
    __shared__ _Float16 Ks[64][64];      // 8 KB  (swizzled)
    __shared__ _Float16 Vs[176][64];     // 22 KB (swizzled, V^T)
    __shared__ _Float16 Ps[4][16][72];   // 9.2 KB per-wave P
    const int tid = threadIdx.x, lane = tid & 63, w = tid >> 6;
    const int lr = lane & 15, lg = lane >> 4;
    const int n = blockIdx.x;
    const int gq = 31 - (n >> 5);                  // LPT: long first
    const int bh = (n & 7) + 8 * ((n >> 3) & 3);   // bh%8 == n%8 (XCD)
    const int b_ = bh >> 4;
    const int qt = gq * 4 + w;
    const int q = qt * 16 + lr;                    // this lane's softmax row

    const _Float16* qp = qh + ((size_t)bh * NT + q) * DKK;
    h8 bq0 = *(const h8*)(qp + lg * 8);
    h8 bq1 = *(const h8*)(qp + 32 + lg * 8);

    const _Float16* kbase = kh + (size_t)bh * KV * DKK;
    const _Float16* vbase = vTh + (size_t)bh * DV * KV;

    f4 o[11];
#pragma unroll
    for (int i = 0; i < 11; i++) o[i] = (f4){0.f, 0.f, 0.f, 0.f};
    float l_acc = 0.f;

    const int nkt = gq + 2;
    const int srow = lane >> 3, sslot = lane & 7;
    const int sc16 = sslot ^ srow;                 // pre-swizzled global col

    for (int kt = 0; kt < nkt; kt++) {
        __syncthreads();                            // everyone done reading prev tile
#pragma unroll
        for (int j = 0; j < 2; j++) {
            int i = w * 2 + j;
            int row = i * 8 + srow;
            load_lds16(&kbase[(size_t)(kt * 64 + row) * DKK + sc16 * 8],
                       (_Float16*)Ks + i * 512);
        }
#pragma unroll
        for (int j = 0; j < 6; j++) {
            int i = w * 6 + j;
            if (i < 22) {
                int row = i * 8 + srow;
                load_lds16(&vbase[(size_t)row * KV + kt * 64 + sc16 * 8],
                           (_Float16*)Vs + i * 512);
            }
        }
        asm volatile("s_waitcnt vmcnt(0)" ::: "memory");
        __syncthreads();                            // tile visible to all

        f4 s[4];
        __builtin_amdgcn_s_setprio(1);
#pragma unroll
        for (int nt = 0; nt < 4; nt++) {
            int krow = nt * 16 + lr;
            h8 ak0 = *(const h8*)&Ks[krow][(lg ^ (lr & 7)) * 8];
            h8 ak1 = *(const h8*)&Ks[krow][((4 + lg) ^ (lr & 7)) * 8];
            f4 st = (f4){0.f, 0.f, 0.f, 0.f};
            st = __builtin_amdgcn_mfma_f32_16x16x32_f16(ak0, bq0, st, 0, 0, 0);
            st = __builtin_amdgcn_mfma_f32_16x16x32_f16(ak1, bq1, st, 0, 0, 0);
            s[nt] = st;
        }
        __builtin_amdgcn_s_setprio(0);

        if (kt + 1 < nkt) {
            // unmasked tiles (kt <= gq): no key computation, no cndmask
#pragma unroll
            for (int nt = 0; nt < 4; nt++) {
                h4 ph;
#pragma unroll
                for (int r = 0; r < 4; r++) {
                    float p = __builtin_exp2f(fminf(s[nt][r], CLAMP_S));
                    l_acc += p;
                    ph[r] = (_Float16)p;
                }
                *(h4*)&Ps[w][lr][nt * 16 + lg * 4] = ph;
            }
        } else {
            // final tile: causal mask active
#pragma unroll
            for (int nt = 0; nt < 4; nt++) {
                h4 ph;
#pragma unroll
                for (int r = 0; r < 4; r++) {
                    int key = kt * 64 + nt * 16 + lg * 4 + r;
                    float sv = fminf(s[nt][r], CLAMP_S);
                    float p = (key <= q + OFF) ? __builtin_exp2f(sv) : 0.f;
                    l_acc += p;
                    ph[r] = (_Float16)p;
                }
                *(h4*)&Ps[w][lr][nt * 16 + lg * 4] = ph;
            }
        }

        __builtin_amdgcn_s_setprio(1);
#pragma unroll
        for (int ks = 0; ks < 2; ks++) {
            h8 ap = *(const h8*)&Ps[w][lr][ks * 32 + lg * 8];
#pragma unroll
            for (int nt = 0; nt < 11; nt++) {
                int vrow = nt * 16 + lr;
                h8 bv = *(const h8*)&Vs[vrow][((ks * 4 + lg) ^ (lr & 7)) * 8];
                o[nt] = __builtin_amdgcn_mfma_f32_16x16x32_f16(ap, bv, o[nt], 0, 0, 0);
            }
        }
        __builtin_amdgcn_s_setprio(0);
    }

    l_acc += __shfl_xor(l_acc, 16);
    l_acc += __shfl_xor(l_acc, 32);
    float lq[4];
#pragma unroll
    for (int r = 0; r < 4; r++) lq[r] = 1.f / __shfl(l_acc, lg * 4 + r);
#pragma unroll
    for (int r = 0; r < 4; r++) {
        int t = qt * 16 + lg * 4 + r;
#pragma unroll
        for (int nt = 0; nt < 11; nt++) {
            atomicAdd(&rot[((size_t)b_ * NT + t) * DV + nt * 16 + lr], o[nt][r] * lq[r]);
        }
    }
}

// ---------------- per-token Kronecker rotation via expm ----------------
__device__ __forceinline__ int triu16(int r, int c) { return r * 15 - (r * (r - 1)) / 2 + (c - r - 1); }
__device__ __forceinline__ int triu8(int r, int c)  { return r * 7  - (r * (r - 1)) / 2 + (c - r - 1); }

__global__ __launch_bounds__(64)
void k_rotate(const float* __restrict__ x, const float* __restrict__ rot,
              float* __restrict__ y) {
    __shared__ float A16[16][16], Ta[16][16], Tb[16][16];
    __shared__ float A8[2][8][8], T8a[2][8][8], T8b[2][8][8];
    __shared__ float pbuf[176];
    __shared__ float xt[1024], t1[1024], t2[1024];
    const int tok = blockIdx.x;
    const int lane = threadIdx.x;

    for (int i = lane; i < 176; i += 64) pbuf[i] = rot[(size_t)tok * DV + i];
    for (int i = lane; i < 1024; i += 64) xt[i] = x[(size_t)tok * NC + i];
    __syncthreads();

#pragma unroll
    for (int j = 0; j < 4; j++) {
        int e = lane * 4 + j, r = e >> 4, c = e & 15;
        float v = 0.f;
        if (r < c) v = pbuf[triu16(r, c)];
        else if (r > c) v = -pbuf[triu16(c, r)];
        A16[r][c] = v;
    }
    {
        int r = lane >> 3, c = lane & 7;
#pragma unroll
        for (int m = 0; m < 2; m++) {
            float v = 0.f;
            if (r < c) v = pbuf[120 + m * 28 + triu8(r, c)];
            else if (r > c) v = -pbuf[120 + m * 28 + triu8(c, r)];
            A8[m][r][c] = v;
        }
    }
    __syncthreads();

    float rn = 0.f;
    if (lane < 16) {
#pragma unroll
        for (int c = 0; c < 16; c++) rn += fabsf(A16[lane][c]);
    }
#pragma unroll
    for (int mm = 1; mm < 16; mm <<= 1) rn = fmaxf(rn, __shfl_xor(rn, mm));
    rn = __shfl(rn, 0);
    int s = 0;
    while (rn > 0.5f && s < 60) { rn *= 0.5f; s++; }
    const float sc16 = exp2f((float)(-s));
    __syncthreads();
#pragma unroll
    for (int j = 0; j < 4; j++) { int e = lane * 4 + j; A16[e >> 4][e & 15] *= sc16; }
    __syncthreads();
#pragma unroll
    for (int j = 0; j < 4; j++) {
        int e = lane * 4 + j, r = e >> 4, c = e & 15;
        Ta[r][c] = (r == c ? 1.f : 0.f) + A16[r][c] * (1.f / 12.f);
    }
    __syncthreads();
    float (*Tc)[16] = Ta, (*Tn)[16] = Tb;
    for (int k = 11; k >= 1; k--) {
#pragma unroll
        for (int j = 0; j < 4; j++) {
            int e = lane * 4 + j, r = e >> 4, c = e & 15;
            float acc = 0.f;
#pragma unroll
            for (int q = 0; q < 16; q++) acc += A16[r][q] * Tc[q][c];
            Tn[r][c] = acc * (1.f / (float)k) + (r == c ? 1.f : 0.f);
        }
        __syncthreads();
        float (*tmp)[16] = Tc; Tc = Tn; Tn = tmp;
    }
    for (int it = 0; it < s; it++) {
#pragma unroll
        for (int j = 0; j < 4; j++) {
            int e = lane * 4 + j, r = e >> 4, c = e & 15;
            float acc = 0.f;
#pragma unroll
            for (int q = 0; q < 16; q++) acc += Tc[r][q] * Tc[q][c];
            Tn[r][c] = acc;
        }
        __syncthreads();
        float (*tmp)[16] = Tc; Tc = Tn; Tn = tmp;
    }

    float (*R2p)[8] = T8a[0];
    float (*R3p)[8] = T8a[1];
    {
        int r = lane >> 3, c = lane & 7;
        for (int m = 0; m < 2; m++) {
            float rn8 = 0.f;
            if (lane < 8) {
#pragma unroll
                for (int cc = 0; cc < 8; cc++) rn8 += fabsf(A8[m][lane][cc]);
            }
#pragma unroll
            for (int mm = 1; mm < 8; mm <<= 1) rn8 = fmaxf(rn8, __shfl_xor(rn8, mm));
            rn8 = __shfl(rn8, 0);
            int s8 = 0;
            while (rn8 > 0.5f && s8 < 60) { rn8 *= 0.5f; s8++; }
            float sc8 = exp2f((float)(-s8));
            __syncthreads();
            A8[m][r][c] *= sc8;
            __syncthreads();
            T8a[m][r][c] = (r == c ? 1.f : 0.f) + A8[m][r][c] * (1.f / 12.f);
            __syncthreads();
            float (*tc)[8] = T8a[m], (*tn)[8] = T8b[m];
            for (int k = 11; k >= 1; k--) {
                float acc = 0.f;
#pragma unroll
                for (int q = 0; q < 8; q++) acc += A8[m][r][q] * tc[q][c];
                tn[r][c] = acc * (1.f / (float)k) + (r == c ? 1.f : 0.f);
                __syncthreads();
                float (*tmp)[8] = tc; tc = tn; tn = tmp;
            }
            for (int it = 0; it < s8; it++) {
                float acc = 0.f;
#pragma unroll
                for (int q = 0; q < 8; q++) acc += tc[r][q] * tc[q][c];
                tn[r][c] = acc;
                __syncthreads();
                float (*tmp)[8] = tc; tc = tn; tn = tmp;
            }
            if (m == 0) R2p = tc; else R3p = tc;
        }
    }
    __syncthreads();

    for (int o = lane; o < 1024; o += 64) {
        int c = o & 7, base = o & ~7;
        float acc = 0.f;
#pragma unroll
        for (int j = 0; j < 8; j++) acc += R3p[c][j] * xt[base + j];
        t1[o] = acc;
    }
    __syncthreads();
    for (int o = lane; o < 1024; o += 64) {
        int c = o & 7, bb = (o >> 3) & 7, a = o >> 6;
        float acc = 0.f;
#pragma unroll
        for (int j = 0; j < 8; j++) acc += R2p[bb][j] * t1[a * 64 + j * 8 + c];
        t2[o] = acc;
    }
    __syncthreads();
    for (int o = lane; o < 1024; o += 64) {
        int rr = o & 63, a = o >> 6;
        float acc = 0.f;
#pragma unroll
        for (int j = 0; j < 16; j++) acc += Tc[a][j] * t2[j * 64 + rr];
        y[(size_t)tok * NC + o] = acc;
    }
}

// ---------------- launcher ----------------
extern "C" void kernel_launch(void* const* d_in, const int* in_sizes, int n_in,
                              void* d_out, int out_size, void* d_ws, size_t ws_size,
                              hipStream_t stream) {
    const float* x   = (const float*)d_in[0];
    const float* ck  = (const float*)d_in[1];
    const float* cv  = (const float*)d_in[2];
    const float* wqk = (const float*)d_in[3];
    const float* wv  = (const float*)d_in[4];

    float* out_y = (float*)d_out;
    float* out_k = out_y + (size_t)NB * NT * NC;
    float* out_v = out_k + (size_t)NB * NH * KV * DKK;

    char* ws = (char*)d_ws;
    _Float16* xh   = (_Float16*)ws;  ws += (size_t)NB * NT * NC * 2;
    _Float16* wqkh = (_Float16*)ws;  ws += (size_t)2 * NH * DKK * NC * 2;   // contiguous with wvh
    _Float16* wvh  = (_Float16*)ws;  ws += (size_t)NH * DV * NC * 2;
    _Float16* qh   = (_Float16*)ws;  ws += (size_t)NB * NH * NT * DKK * 2;
    _Float16* kh   = (_Float16*)ws;  ws += (size_t)NB * NH * KV * DKK * 2;
    _Float16* vTh  = (_Float16*)ws;  ws += (size_t)NB * NH * DV * KV * 2;
    float*    rotb = (float*)ws;     ws += (size_t)NB * NT * DV * 4;

    k_prep_a<<<dim3((PREPA_END + 255) / 256), dim3(256), 0, stream>>>(
        x, wqk, wv, xh, wqkh, wvh, rotb);
    k_prep_b<<<dim3((PREPB_END + 255) / 256), dim3(256), 0, stream>>>(
        ck, cv, out_k, kh, out_v, vTh);

    k_gemm_fused<<<dim3(1216), dim3(256), 0, stream>>>(xh, wqkh, qh, kh, out_k, vTh, out_v);

    k_attn<<<dim3(1024), dim3(256), 0, stream>>>(qh, kh, vTh, rotb);

    k_rotate<<<dim3(NB * NT), dim3(64), 0, stream>>>(x, rotb, out_y);
}